// Round 3
// baseline (662.510 us; speedup 1.0000x reference)
//
#include <hip/hip_runtime.h>
#include <math.h>

// Problem constants (match reference file)
#define N_NODES_C 100000
#define DIM_C     128
#define DMSG_C    512
#define N_EDGES_C 200000

// GEMM geometry: 64 nodes/block (4 node-groups of 16), 512 gate rows = 32 tiles
#define GROUPS_PAD 6252            // 1563 blocks * 4 groups
#define NODES_PAD  (GROUPS_PAD*16) // 100032
#define XKK 12                     // X = [self|other|ef] = 384 cols = 12 kk-chunks of 32

typedef __attribute__((ext_vector_type(8))) __bf16 bf16x8;
typedef __attribute__((ext_vector_type(4))) float  f32x4;

__device__ __forceinline__ float sigmoidf_(float x) { return 1.0f / (1.0f + __expf(-x)); }
__device__ __forceinline__ unsigned short f2bf(float x) {
    union { float f; unsigned u; } v; v.f = x;
    unsigned r = v.u + 0x7FFFu + ((v.u >> 16) & 1u);   // RNE
    return (unsigned short)(r >> 16);
}
__device__ __forceinline__ void st8(void* p, float4 lo, float4 hi) {
    union { bf16x8 v; unsigned short u[8]; } r;
    r.u[0] = f2bf(lo.x); r.u[1] = f2bf(lo.y); r.u[2] = f2bf(lo.z); r.u[3] = f2bf(lo.w);
    r.u[4] = f2bf(hi.x); r.u[5] = f2bf(hi.y); r.u[6] = f2bf(hi.z); r.u[7] = f2bf(hi.w);
    *(bf16x8*)p = r.v;
}

// ---- last occurrence of each node in edge order ----
__global__ void scatter_last_kernel(const int* __restrict__ src, const int* __restrict__ dst,
                                    int* __restrict__ idx_s, int* __restrict__ idx_d) {
    int e = blockIdx.x * blockDim.x + threadIdx.x;
    if (e < N_EDGES_C) {
        atomicMax(&idx_s[src[e]], e);
        atomicMax(&idx_d[dst[e]], e);
    }
}

// =====================  MAIN (split) PATH  =====================
// Wsw[tile][kk][lane][8]: B-fragment order. tile T: packed gate rows T*16+(l&15):
//   rows 0..127 r, 128..255 z, 256..383 i_n (W_ih), 384..511 h_n (W_hh rows 256..383)
// K map: 0..127 self, 128..255 other, 256..383 ef, 384..511 enc, 512..639 h
__global__ void build_wallsw_kernel(const float* __restrict__ W_ih, const float* __restrict__ W_hh,
                                    unsigned short* __restrict__ Wsw) {
    int id = blockIdx.x * 256 + threadIdx.x;           // 32*20*64 = 40960
    if (id >= 32 * 20 * 64) return;
    int tile = id / 1280, r = id - tile * 1280, kk = r >> 6, l = r & 63;
    int pr = tile * 16 + (l & 15);
    int k0 = kk * 32 + ((l >> 4) & 3) * 8;
    float v[8];
#pragma unroll
    for (int j = 0; j < 8; ++j) {
        int k = k0 + j;
        if (pr < 256)      v[j] = (k < 512) ? W_ih[(long)pr * DMSG_C + k] : W_hh[(long)pr * DIM_C + (k - 512)];
        else if (pr < 384) v[j] = (k < 512) ? W_ih[(long)pr * DMSG_C + k] : 0.0f;
        else               v[j] = (k >= 512) ? W_hh[(long)(pr - 128) * DIM_C + (k - 512)] : 0.0f;
    }
    union { bf16x8 bv; unsigned short u[8]; } o;
#pragma unroll
    for (int j = 0; j < 8; ++j) o.u[j] = f2bf(v[j]);
    *(bf16x8*)((char*)Wsw + ((size_t)(tile * 20 + kk) << 10) + ((size_t)l << 4)) = o.bv;
}

// Gather: 16 nodes/block. Builds Xs/Xd (A-frag-swizzled bf16), dt arrays, out_lu,
// and the inactive-pass0 copy of memory into out_mem.
__global__ __launch_bounds__(256) void gather_kernel(
    const float* __restrict__ memory, const float* __restrict__ last_update,
    const float* __restrict__ edge_times, const float* __restrict__ edge_feat,
    const int* __restrict__ src, const int* __restrict__ dst,
    const int* __restrict__ idx_s, const int* __restrict__ idx_d,
    float* __restrict__ dt_s, float* __restrict__ dt_d,
    unsigned short* __restrict__ Xs, unsigned short* __restrict__ Xd,
    float* __restrict__ out_mem, float* __restrict__ out_lu)
{
    __shared__ int es_l[16], ed_l[16], os_l[16], od_l[16];
    const int t = threadIdx.x;
    const int base = blockIdx.x * 16;
    if (t < 16) {
        const int n = base + t;
        const int es = idx_s[n], ed = idx_d[n];
        const int eus = es < 0 ? 0 : es, eud = ed < 0 ? 0 : ed;
        es_l[t] = es; ed_l[t] = ed;
        os_l[t] = dst[eus]; od_l[t] = src[eud];
        const float lun = last_update[n];
        const float ts = edge_times[eus], td = edge_times[eud];
        dt_s[n] = ts - lun; dt_d[n] = td - lun;
        out_lu[n] = (ed >= 0) ? td : ((es >= 0) ? ts : lun);
    }
    __syncthreads();
    const int m = t & 15, q = t >> 4;                  // node-in-block, col-chunk (8 cols)
    const int n = base + m;
    const size_t g = blockIdx.x;                       // node-group == block
    const int es = es_l[m];
    const int eus = (es < 0) ? 0 : es;
    const int eud = (ed_l[m] < 0) ? 0 : ed_l[m];
    const float4* self_p = (const float4*)(memory + (size_t)n * DIM_C + q * 8);
    const float4* oS_p   = (const float4*)(memory + (size_t)os_l[m] * DIM_C + q * 8);
    const float4* oD_p   = (const float4*)(memory + (size_t)od_l[m] * DIM_C + q * 8);
    const float4* eS_p   = (const float4*)(edge_feat + (size_t)eus * DIM_C + q * 8);
    const float4* eD_p   = (const float4*)(edge_feat + (size_t)eud * DIM_C + q * 8);
    float4 s0 = self_p[0], s1 = self_p[1];
    float4 a0 = oS_p[0],   a1 = oS_p[1];
    float4 b0 = oD_p[0],   b1 = oD_p[1];
    float4 c0 = eS_p[0],   c1 = eS_p[1];
    float4 d0 = eD_p[0],   d1 = eD_p[1];
    const int kkq = q >> 2;
    const size_t laneoff = (size_t)(((q & 3) * 16 + m)) << 4;
    char* XsB = (char*)Xs; char* XdB = (char*)Xd;
#define XOFF(kk) ((((g * XKK) + (kk)) << 10) + laneoff)
    st8(XsB + XOFF(kkq),     s0, s1);
    st8(XsB + XOFF(4 + kkq), a0, a1);
    st8(XsB + XOFF(8 + kkq), c0, c1);
    st8(XdB + XOFF(kkq),     s0, s1);
    st8(XdB + XOFF(4 + kkq), b0, b1);
    st8(XdB + XOFF(8 + kkq), d0, d1);
#undef XOFF
    if (es < 0) {   // inactive in pass0: seed out_mem with original memory row
        float4* op = (float4*)(out_mem + (size_t)n * DIM_C + q * 8);
        op[0] = s0; op[1] = s1;
    }
}

// GEMM+GRU pass, R5: counted-vmcnt global_load_lds DMA pipeline.
// 64 nodes/block (4 groups), 4 waves; wave w owns gate-tiles {w,w+4,...,w+28}.
//
// LDS map (128 KB, 1 block/CU):
//   [0,48K)    B double-buffer: [p][wave][s6][1024]  (wave-PRIVATE -> no loop barriers)
//   [48K,64K)  Elds[4 kkE][4 nt][64 lane][8] bf16  (ENC A-fragments, computed once)
//   [64K,128K) A: [nt][16 chunks][1024]  (chunks 0..11 = X, 12..15 = H mirror)
// Prologue: wave w DMA-stages A chunks of group w (16x global_load_lds) + B(st=0),
// computes Elds chunk w (VALU overlaps DMA), one __syncthreads().
// Main loop (no barriers): stage B(st+1) -> s_waitcnt vmcnt(6) -> ds_read A,B -> 24 MFMA.
// Step order: st 0..11 = X (kw=st, slots 0..5), st 12..15 = H (kw=st+4, slots
// {0,1,2,3,6,7}), st 16..19 = ENC from Elds (kw=st-4, slots 0..5).
template <int PASS>
__global__ __launch_bounds__(256, 1) void gemm_pass_kernel(
    const float* __restrict__ memory,
    const unsigned short* __restrict__ Wsw,
    const float* __restrict__ b_ih, const float* __restrict__ b_hh,
    const unsigned short* __restrict__ Xsw,
    unsigned short* Hmir,                      // = Xs (self-block mirror; aliases Xsw in pass0)
    const float* __restrict__ dtp, const int* __restrict__ idxp,
    float* __restrict__ out_mem)
{
    __shared__ __align__(1024) char lds[131072];
    const int t = threadIdx.x;
    const int w = t >> 6, lane = t & 63, quad = lane >> 4, c = lane & 15;
    const long g0 = (long)blockIdx.x * 4;
    const char* Xb = (const char*)Xsw;
    const char* Hb = (const char*)Hmir;
    const char* Wb = (const char*)Wsw;
    const size_t laneoff = (size_t)lane << 4;

#define BOFF(p, wv, s6) (((((p) << 2) | (wv)) * 6 + (s6)) << 10)
#define AOFF(nt, cc)    (65536 + (((nt) * 16 + (cc)) << 10))
    unsigned short* Eb = (unsigned short*)(lds + 49152);

    // DMA: per-lane global src (base + lane*16), wave-uniform LDS dest (HW adds lane*16)
    auto stage = [&](const char* gsrc_base, int ldsoff) {
        __builtin_amdgcn_global_load_lds(
            (const __attribute__((address_space(1))) void*)(gsrc_base + laneoff),
            (__attribute__((address_space(3))) void*)(lds + ldsoff), 16, 0, 0);
    };

    // ---- prologue: stage A (group w, 16 chunks) + B(st=0); compute Elds chunk w ----
#pragma unroll
    for (int cc = 0; cc < 16; ++cc) {
        const char* src = (cc < 12)
            ? (Xb + (((g0 + w) * XKK + cc) << 10))
            : (Hb + (((g0 + w) * XKK + (cc - 12)) << 10));
        stage(src, AOFF(w, cc));
    }
#pragma unroll
    for (int s6 = 0; s6 < 6; ++s6)
        stage(Wb + ((size_t)((w + 4 * s6) * 20 + 0) << 10), BOFF(0, w, s6));

    {   // ENC fragments: Elds[w][nt][lane][8] = cos(dt * w_f), f = w*32 + quad*8 + j
        const int f0 = w * 32 + quad * 8;
        float wf[8];
#pragma unroll
        for (int j = 0; j < 8; ++j) wf[j] = __expf(-0.16317532f * (float)(f0 + j));
#pragma unroll
        for (int nt = 0; nt < 4; ++nt) {
            const float dtv = dtp[(g0 + nt) * 16 + c];
            union { bf16x8 v; unsigned short u[8]; } r;
#pragma unroll
            for (int j = 0; j < 8; ++j) r.u[j] = f2bf(__cosf(dtv * wf[j]));
            *(bf16x8*)(Eb + ((size_t)((w * 4 + nt) * 64 + lane) * 8)) = r.v;
        }
    }
    __syncthreads();   // drains all DMA (vmcnt 0) + Elds visible to all waves

    f32x4 acc[8][4];
#pragma unroll
    for (int s = 0; s < 8; ++s)
#pragma unroll
        for (int nt = 0; nt < 4; ++nt) acc[s][nt] = (f32x4){0.f, 0.f, 0.f, 0.f};

    // ---- main loop: per-wave independent DMA pipeline, no barriers ----
#pragma unroll
    for (int st = 0; st < 20; ++st) {
        const int p = st & 1;
        if (st < 19) {
            const int stn = st + 1;
            const int kwn = (stn < 12) ? stn : ((stn < 16) ? stn + 4 : stn - 4);
            const bool hn = (stn >= 12 && stn < 16);
#pragma unroll
            for (int s6 = 0; s6 < 6; ++s6) {
                const int sl = hn ? ((s6 < 4) ? s6 : s6 + 2) : s6;
                stage(Wb + ((size_t)((w + 4 * sl) * 20 + kwn) << 10), BOFF(p ^ 1, w, s6));
            }
            asm volatile("s_waitcnt vmcnt(6)" ::: "memory");   // B(st) landed; B(st+1) in flight
        } else {
            asm volatile("s_waitcnt vmcnt(0)" ::: "memory");
        }
        __builtin_amdgcn_sched_barrier(0);

        bf16x8 A[4];
        if (st < 16) {
#pragma unroll
            for (int nt = 0; nt < 4; ++nt)
                A[nt] = *(const bf16x8*)(lds + AOFF(nt, st) + laneoff);
        } else {
#pragma unroll
            for (int nt = 0; nt < 4; ++nt)
                A[nt] = *(const bf16x8*)(Eb + ((size_t)(((st - 16) * 4 + nt) * 64 + lane) * 8));
        }
        const bool hph = (st >= 12 && st < 16);
        __builtin_amdgcn_s_setprio(1);
#pragma unroll
        for (int s6 = 0; s6 < 6; ++s6) {
            const int s = hph ? ((s6 < 4) ? s6 : s6 + 2) : s6;
            bf16x8 B = *(const bf16x8*)(lds + BOFF(p, w, s6) + laneoff);
#pragma unroll
            for (int nt = 0; nt < 4; ++nt)
                acc[s][nt] = __builtin_amdgcn_mfma_f32_16x16x32_bf16(A[nt], B, acc[s][nt], 0, 0, 0);
        }
        __builtin_amdgcn_s_setprio(0);
    }
#undef BOFF
#undef AOFF

    // Epilogue: lane owns node = (g0+nt)*16 + quad*4 + reg, dims j = (w+4p)*16 + c
    const float* hsrc = (PASS == 0) ? memory : out_mem;
#pragma unroll
    for (int p = 0; p < 2; ++p) {
        const int j = (w + 4 * p) * 16 + c;
        const float br = b_ih[j] + b_hh[j];
        const float bz = b_ih[128 + j] + b_hh[128 + j];
        const float bi = b_ih[256 + j];
        const float bh = b_hh[256 + j];
        // bf16-mirror address components for dim j (A-frag layout within self block)
        const int kkm = j >> 5;
        const int q2  = (j >> 3) & 3;
        const int bb  = j & 7;
#pragma unroll
        for (int nt = 0; nt < 4; ++nt) {
#pragma unroll
            for (int reg = 0; reg < 4; ++reg) {
                const long n = (g0 + nt) * 16 + quad * 4 + reg;
                if (n < N_NODES_C) {
                    const int e = idxp[n];
                    if (e >= 0) {
                        const float r  = sigmoidf_(acc[0 + p][nt][reg] + br);
                        const float z  = sigmoidf_(acc[2 + p][nt][reg] + bz);
                        const float nn = tanhf(acc[4 + p][nt][reg] + bi + r * (acc[6 + p][nt][reg] + bh));
                        const float h  = hsrc[(size_t)n * DIM_C + j];
                        const float hnew = (1.0f - z) * nn + z * h;
                        out_mem[(size_t)n * DIM_C + j] = hnew;
                        if (PASS == 0) {
                            const int row = quad * 4 + reg;
                            *(unsigned short*)((char*)Hmir + (((g0 + nt) * XKK + kkm) << 10)
                                               + ((q2 * 16 + row) << 4) + (bb << 1)) = f2bf(hnew);
                        }
                    }
                }
            }
        }
    }
}

// =====================  FALLBACK (R2 fused) PATH  =====================
#define NODES_PB  32
#define LDSW      648
#define WROWS     512
#define NXF       640

__global__ void build_wall_kernel(const float* __restrict__ W_ih, const float* __restrict__ W_hh,
                                  unsigned short* __restrict__ Wall) {
    int i = blockIdx.x * 256 + threadIdx.x;
    if (i >= WROWS * NXF) return;
    int r = i / NXF, k = i - r * NXF;
    float v;
    if (r < 256)      v = (k < 512) ? W_ih[(long)r * DMSG_C + k] : W_hh[(long)r * DIM_C + (k - 512)];
    else if (r < 384) v = (k < 512) ? W_ih[(long)r * DMSG_C + k] : 0.0f;
    else              v = (k >= 512) ? W_hh[(long)(r - 128) * DIM_C + (k - 512)] : 0.0f;
    Wall[i] = f2bf(v);
}

template <int PASS>
__global__ __launch_bounds__(256) void gru_mfma_kernel(
    const float* __restrict__ memory, const float* __restrict__ last_update,
    const unsigned short* __restrict__ Wall,
    const float* __restrict__ b_ih, const float* __restrict__ b_hh,
    const float* __restrict__ edge_times, const float* __restrict__ edge_feat,
    const int* __restrict__ src, const int* __restrict__ dst,
    const int* __restrict__ idx,
    float* __restrict__ out_mem, float* __restrict__ out_lu)
{
    __shared__ __align__(16) unsigned short Xl[NODES_PB][LDSW];
    __shared__ int eidx[NODES_PB];
    const int t = threadIdx.x;
    const int base = blockIdx.x * NODES_PB;
    if (t < NODES_PB) eidx[t] = idx[base + t];
    __syncthreads();
    const int tt = t & 127;
    const int sh = t >> 7;
    const float wfreq = __expf(-0.16317532f * (float)tt);
    for (int s0 = 0; s0 < NODES_PB; s0 += 2) {
        const int s = s0 + sh;
        const int n = base + s;
        const int e = eidx[s];
        const int eu = (e >= 0) ? e : 0;
        const int other = (PASS == 0) ? dst[eu] : src[eu];
        const float mself = memory[(long)n * DIM_C + tt];
        const float moth  = memory[(long)other * DIM_C + tt];
        const float ef    = edge_feat[(long)eu * DIM_C + tt];
        const float dt    = edge_times[eu] - last_update[n];
        const float enc   = __cosf(dt * wfreq);
        const float hv    = (PASS == 0) ? mself : out_mem[(long)n * DIM_C + tt];
        Xl[s][tt]       = f2bf(mself);
        Xl[s][128 + tt] = f2bf(moth);
        Xl[s][256 + tt] = f2bf(ef);
        Xl[s][384 + tt] = f2bf(enc);
        Xl[s][512 + tt] = f2bf(hv);
    }
    __syncthreads();
    const int w = t >> 6, lane = t & 63;
    const int quad = lane >> 4, c = lane & 15;
    f32x4 acc[8][2];
#pragma unroll
    for (int i = 0; i < 8; ++i)
#pragma unroll
        for (int mt = 0; mt < 2; ++mt) acc[i][mt] = (f32x4){0.f, 0.f, 0.f, 0.f};
    const unsigned short* wrow[8];
#pragma unroll
    for (int i = 0; i < 8; ++i)
        wrow[i] = Wall + (long)((w + 4 * i) * 16 + c) * NXF + quad * 8;
    for (int kk = 0; kk < 16; ++kk) {
        const int k0 = kk * 32;
        bf16x8 a0 = *(const bf16x8*)&Xl[c][k0 + quad * 8];
        bf16x8 a1 = *(const bf16x8*)&Xl[16 + c][k0 + quad * 8];
#pragma unroll
        for (int i = 0; i < 6; ++i) {
            bf16x8 b = *(const bf16x8*)(wrow[i] + k0);
            acc[i][0] = __builtin_amdgcn_mfma_f32_16x16x32_bf16(a0, b, acc[i][0], 0, 0, 0);
            acc[i][1] = __builtin_amdgcn_mfma_f32_16x16x32_bf16(a1, b, acc[i][1], 0, 0, 0);
        }
    }
    for (int kk = 16; kk < 20; ++kk) {
        const int k0 = kk * 32;
        bf16x8 a0 = *(const bf16x8*)&Xl[c][k0 + quad * 8];
        bf16x8 a1 = *(const bf16x8*)&Xl[16 + c][k0 + quad * 8];
#pragma unroll
        for (int ii = 0; ii < 6; ++ii) {
            const int i = (ii < 4) ? ii : ii + 2;
            bf16x8 b = *(const bf16x8*)(wrow[i] + k0);
            acc[i][0] = __builtin_amdgcn_mfma_f32_16x16x32_bf16(a0, b, acc[i][0], 0, 0, 0);
            acc[i][1] = __builtin_amdgcn_mfma_f32_16x16x32_bf16(a1, b, acc[i][1], 0, 0, 0);
        }
    }
    const float* hsrc = (PASS == 0) ? memory : out_mem;
#pragma unroll
    for (int p = 0; p < 2; ++p) {
        const int j = (w + 4 * p) * 16 + c;
        const float br = b_ih[j] + b_hh[j];
        const float bz = b_ih[128 + j] + b_hh[128 + j];
        const float bi = b_ih[256 + j];
        const float bh = b_hh[256 + j];
#pragma unroll
        for (int mt = 0; mt < 2; ++mt) {
#pragma unroll
            for (int reg = 0; reg < 4; ++reg) {
                const int ml = mt * 16 + quad * 4 + reg;
                const int n = base + ml;
                const int e = eidx[ml];
                const float h = hsrc[(long)n * DIM_C + j];
                if (e >= 0) {
                    const float r  = sigmoidf_(acc[p][mt][reg] + br);
                    const float z  = sigmoidf_(acc[p + 2][mt][reg] + bz);
                    const float nn = tanhf(acc[p + 4][mt][reg] + bi + r * (acc[p + 6][mt][reg] + bh));
                    out_mem[(long)n * DIM_C + j] = (1.0f - z) * nn + z * h;
                } else if (PASS == 0) {
                    out_mem[(long)n * DIM_C + j] = h;
                }
            }
        }
    }
    if (t < NODES_PB) {
        const int n = base + t;
        const int e = eidx[t];
        if (e >= 0)         out_lu[n] = edge_times[e];
        else if (PASS == 0) out_lu[n] = last_update[n];
    }
}

// =====================  LAUNCH  =====================
extern "C" void kernel_launch(void* const* d_in, const int* in_sizes, int n_in,
                              void* d_out, int out_size, void* d_ws, size_t ws_size,
                              hipStream_t stream) {
    const float* memory      = (const float*)d_in[0];
    const float* last_update = (const float*)d_in[1];
    const float* W_ih        = (const float*)d_in[2];
    const float* W_hh        = (const float*)d_in[3];
    const float* b_ih        = (const float*)d_in[4];
    const float* b_hh        = (const float*)d_in[5];
    const float* edge_times  = (const float*)d_in[6];
    const float* edge_feat   = (const float*)d_in[7];
    const int*   src         = (const int*)d_in[8];
    const int*   dst         = (const int*)d_in[9];

    float* out_mem = (float*)d_out;
    float* out_lu  = out_mem + (size_t)N_NODES_C * DIM_C;

    // ws layout (main path)
    const size_t sIdx  = (size_t)NODES_PAD * 4;           // 400128 B each
    const size_t sDt   = (size_t)NODES_PAD * 4;
    const size_t sWall = (size_t)32 * 20 * 1024;          // 655360 B
    const size_t sX    = (size_t)GROUPS_PAD * XKK * 1024; // 76.8 MB each
    const size_t oIdxS = 0, oIdxD = oIdxS + sIdx, oDtS = oIdxD + sIdx, oDtD = oDtS + sDt;
    const size_t oWall = oDtD + sDt, oXs = oWall + sWall, oXd = oXs + sX;
    const size_t need  = oXd + sX;                        // ~149 MB

    if (ws_size >= need) {
        int* idx_s = (int*)((char*)d_ws + oIdxS);
        int* idx_d = (int*)((char*)d_ws + oIdxD);
        float* dt_s = (float*)((char*)d_ws + oDtS);
        float* dt_d = (float*)((char*)d_ws + oDtD);
        unsigned short* Wsw = (unsigned short*)((char*)d_ws + oWall);
        unsigned short* Xs  = (unsigned short*)((char*)d_ws + oXs);
        unsigned short* Xd  = (unsigned short*)((char*)d_ws + oXd);

        hipMemsetAsync(d_ws, 0xFF, 2 * sIdx, stream);     // idx arrays = -1
        scatter_last_kernel<<<(N_EDGES_C + 255) / 256, 256, 0, stream>>>(src, dst, idx_s, idx_d);
        build_wallsw_kernel<<<160, 256, 0, stream>>>(W_ih, W_hh, Wsw);
        gather_kernel<<<N_NODES_C / 16, 256, 0, stream>>>(
            memory, last_update, edge_times, edge_feat, src, dst,
            idx_s, idx_d, dt_s, dt_d, Xs, Xd, out_mem, out_lu);
        gemm_pass_kernel<0><<<GROUPS_PAD / 4, 256, 0, stream>>>(
            memory, Wsw, b_ih, b_hh, Xs, Xs, dt_s, idx_s, out_mem);
        gemm_pass_kernel<1><<<GROUPS_PAD / 4, 256, 0, stream>>>(
            memory, Wsw, b_ih, b_hh, Xd, Xs, dt_d, idx_d, out_mem);
    } else {
        // R2 fused fallback (needs ~1.5 MB ws)
        int* idx_s = (int*)d_ws;
        int* idx_d = idx_s + N_NODES_C;
        unsigned short* Wall = (unsigned short*)((char*)d_ws + 2 * N_NODES_C * sizeof(int));
        hipMemsetAsync(d_ws, 0xFF, 2 * N_NODES_C * sizeof(int), stream);
        scatter_last_kernel<<<(N_EDGES_C + 255) / 256, 256, 0, stream>>>(src, dst, idx_s, idx_d);
        build_wall_kernel<<<(WROWS * NXF + 255) / 256, 256, 0, stream>>>(W_ih, W_hh, Wall);
        gru_mfma_kernel<0><<<N_NODES_C / NODES_PB, 256, 0, stream>>>(
            memory, last_update, Wall, b_ih, b_hh, edge_times, edge_feat,
            src, dst, idx_s, out_mem, out_lu);
        gru_mfma_kernel<1><<<N_NODES_C / NODES_PB, 256, 0, stream>>>(
            memory, last_update, Wall, b_ih, b_hh, edge_times, edge_feat,
            src, dst, idx_d, out_mem, out_lu);
    }
}

// Round 4
// 495.812 us; speedup vs baseline: 1.3362x; 1.3362x over previous
//
#include <hip/hip_runtime.h>
#include <math.h>

// Problem constants (match reference file)
#define N_NODES_C 100000
#define DIM_C     128
#define DMSG_C    512
#define N_EDGES_C 200000

// GEMM geometry: 64 nodes/block (4 node-groups of 16), 512 gate rows = 32 tiles
#define GROUPS_PAD 6252            // 1563 blocks * 4 groups
#define NODES_PAD  (GROUPS_PAD*16) // 100032
#define XKK 12                     // X = [self|other|ef] = 384 cols = 12 kk-chunks of 32

typedef __attribute__((ext_vector_type(8))) __bf16 bf16x8;
typedef __attribute__((ext_vector_type(4))) float  f32x4;

__device__ __forceinline__ float sigmoidf_(float x) { return 1.0f / (1.0f + __expf(-x)); }
// fast tanh: 1 - 2/(e^{2x}+1); exact at +/-inf, ~1e-7 abs err mid-range (<< bf16 gemm noise)
__device__ __forceinline__ float tanhf_(float x) { return 1.0f - 2.0f / (__expf(2.0f * x) + 1.0f); }
__device__ __forceinline__ unsigned short f2bf(float x) {
    union { float f; unsigned u; } v; v.f = x;
    unsigned r = v.u + 0x7FFFu + ((v.u >> 16) & 1u);   // RNE
    return (unsigned short)(r >> 16);
}
__device__ __forceinline__ void st8(void* p, float4 lo, float4 hi) {
    union { bf16x8 v; unsigned short u[8]; } r;
    r.u[0] = f2bf(lo.x); r.u[1] = f2bf(lo.y); r.u[2] = f2bf(lo.z); r.u[3] = f2bf(lo.w);
    r.u[4] = f2bf(hi.x); r.u[5] = f2bf(hi.y); r.u[6] = f2bf(hi.z); r.u[7] = f2bf(hi.w);
    *(bf16x8*)p = r.v;
}

// ---- last occurrence of each node in edge order ----
__global__ void scatter_last_kernel(const int* __restrict__ src, const int* __restrict__ dst,
                                    int* __restrict__ idx_s, int* __restrict__ idx_d) {
    int e = blockIdx.x * blockDim.x + threadIdx.x;
    if (e < N_EDGES_C) {
        atomicMax(&idx_s[src[e]], e);
        atomicMax(&idx_d[dst[e]], e);
    }
}

// =====================  MAIN (split) PATH  =====================
// Wsw[tile][kk][lane][8]: B-fragment order. tile T: packed gate rows T*16+(l&15):
//   rows 0..127 r, 128..255 z, 256..383 i_n (W_ih), 384..511 h_n (W_hh rows 256..383)
// K map: 0..127 self, 128..255 other, 256..383 ef, 384..511 enc, 512..639 h
__global__ void build_wallsw_kernel(const float* __restrict__ W_ih, const float* __restrict__ W_hh,
                                    unsigned short* __restrict__ Wsw) {
    int id = blockIdx.x * 256 + threadIdx.x;           // 32*20*64 = 40960
    if (id >= 32 * 20 * 64) return;
    int tile = id / 1280, r = id - tile * 1280, kk = r >> 6, l = r & 63;
    int pr = tile * 16 + (l & 15);
    int k0 = kk * 32 + ((l >> 4) & 3) * 8;
    float v[8];
#pragma unroll
    for (int j = 0; j < 8; ++j) {
        int k = k0 + j;
        if (pr < 256)      v[j] = (k < 512) ? W_ih[(long)pr * DMSG_C + k] : W_hh[(long)pr * DIM_C + (k - 512)];
        else if (pr < 384) v[j] = (k < 512) ? W_ih[(long)pr * DMSG_C + k] : 0.0f;
        else               v[j] = (k >= 512) ? W_hh[(long)(pr - 128) * DIM_C + (k - 512)] : 0.0f;
    }
    union { bf16x8 bv; unsigned short u[8]; } o;
#pragma unroll
    for (int j = 0; j < 8; ++j) o.u[j] = f2bf(v[j]);
    *(bf16x8*)((char*)Wsw + ((size_t)(tile * 20 + kk) << 10) + ((size_t)l << 4)) = o.bv;
}

// Gather: 16 nodes/block. Builds Xs/Xd (A-frag-swizzled bf16), dt arrays, out_lu,
// and the inactive-pass0 copy of memory into out_mem.
__global__ __launch_bounds__(256) void gather_kernel(
    const float* __restrict__ memory, const float* __restrict__ last_update,
    const float* __restrict__ edge_times, const float* __restrict__ edge_feat,
    const int* __restrict__ src, const int* __restrict__ dst,
    const int* __restrict__ idx_s, const int* __restrict__ idx_d,
    float* __restrict__ dt_s, float* __restrict__ dt_d,
    unsigned short* __restrict__ Xs, unsigned short* __restrict__ Xd,
    float* __restrict__ out_mem, float* __restrict__ out_lu)
{
    __shared__ int es_l[16], ed_l[16], os_l[16], od_l[16];
    const int t = threadIdx.x;
    const int base = blockIdx.x * 16;
    if (t < 16) {
        const int n = base + t;
        const int es = idx_s[n], ed = idx_d[n];
        const int eus = es < 0 ? 0 : es, eud = ed < 0 ? 0 : ed;
        es_l[t] = es; ed_l[t] = ed;
        os_l[t] = dst[eus]; od_l[t] = src[eud];
        const float lun = last_update[n];
        const float ts = edge_times[eus], td = edge_times[eud];
        dt_s[n] = ts - lun; dt_d[n] = td - lun;
        out_lu[n] = (ed >= 0) ? td : ((es >= 0) ? ts : lun);
    }
    __syncthreads();
    const int m = t & 15, q = t >> 4;                  // node-in-block, col-chunk (8 cols)
    const int n = base + m;
    const size_t g = blockIdx.x;                       // node-group == block
    const int es = es_l[m];
    const int eus = (es < 0) ? 0 : es;
    const int eud = (ed_l[m] < 0) ? 0 : ed_l[m];
    const float4* self_p = (const float4*)(memory + (size_t)n * DIM_C + q * 8);
    const float4* oS_p   = (const float4*)(memory + (size_t)os_l[m] * DIM_C + q * 8);
    const float4* oD_p   = (const float4*)(memory + (size_t)od_l[m] * DIM_C + q * 8);
    const float4* eS_p   = (const float4*)(edge_feat + (size_t)eus * DIM_C + q * 8);
    const float4* eD_p   = (const float4*)(edge_feat + (size_t)eud * DIM_C + q * 8);
    float4 s0 = self_p[0], s1 = self_p[1];
    float4 a0 = oS_p[0],   a1 = oS_p[1];
    float4 b0 = oD_p[0],   b1 = oD_p[1];
    float4 c0 = eS_p[0],   c1 = eS_p[1];
    float4 d0 = eD_p[0],   d1 = eD_p[1];
    const int kkq = q >> 2;
    const size_t laneoff = (size_t)(((q & 3) * 16 + m)) << 4;
    char* XsB = (char*)Xs; char* XdB = (char*)Xd;
#define XOFF(kk) ((((g * XKK) + (kk)) << 10) + laneoff)
    st8(XsB + XOFF(kkq),     s0, s1);
    st8(XsB + XOFF(4 + kkq), a0, a1);
    st8(XsB + XOFF(8 + kkq), c0, c1);
    st8(XdB + XOFF(kkq),     s0, s1);
    st8(XdB + XOFF(4 + kkq), b0, b1);
    st8(XdB + XOFF(8 + kkq), d0, d1);
#undef XOFF
    if (es < 0) {   // inactive in pass0: seed out_mem with original memory row
        float4* op = (float4*)(out_mem + (size_t)n * DIM_C + q * 8);
        op[0] = s0; op[1] = s1;
    }
}

// GEMM+GRU pass, R6. 256 thr = 4 independent waves over the same 64 nodes.
// Wave w owns gate-tiles {w,w+4,...,w+28} = slots {r0,r1,z0,z1,i0,i1,h0,h1}.
// No LDS, no barriers.
//
// R6 root-cause fix (R2-R5 post-mortem: per-wave time was invariant at
// ~480 cyc PER LOAD — hipcc emits just-in-time load→wait→use per B tile,
// serializing 10 full-latency round-trips per k-step):
//  - ALL loads of a k-step batched into named registers (A0-3, B0-5) issued
//    back-to-back before the 24-MFMA cluster → ONE latency exposure per step
//  - ENC phase: B loads issued BEFORE the cos/pack VALU (overlap)
//  - epilogue: idxp/hsrc loads batched into arrays before gate math
//  - library tanhf → __expf-based tanh
// Step order: kk 0..11 X (slots 0..5), hc 0..3 = H mirror (W kk 16..19,
// slots {0,1,2,3,6,7}), ec 0..3 = ENC (W kk 12..15, slots 0..5).
template <int PASS>
__global__ __launch_bounds__(256, 2) void gemm_pass_kernel(
    const float* __restrict__ memory,
    const unsigned short* __restrict__ Wsw,
    const float* __restrict__ b_ih, const float* __restrict__ b_hh,
    const unsigned short* __restrict__ Xsw,
    unsigned short* Hmir,                      // = Xs (self-block mirror; aliases Xsw in pass0)
    const float* __restrict__ dtp, const int* __restrict__ idxp,
    float* __restrict__ out_mem)
{
    const int t = threadIdx.x;
    const int w = t >> 6, lane = t & 63, quad = lane >> 4, c = lane & 15;
    const long g0 = (long)blockIdx.x * 4;
    const char* Xb = (const char*)Xsw;
    const char* Hb = (const char*)Hmir;
    const char* Wb = (const char*)Wsw;
    const size_t laneoff = (size_t)lane << 4;

    // dt values (batched early; used only in ENC phase much later)
    float dtv[4];
#pragma unroll
    for (int nt = 0; nt < 4; ++nt) dtv[nt] = dtp[(g0 + nt) * 16 + c];

    f32x4 acc[8][4];
#pragma unroll
    for (int s = 0; s < 8; ++s)
#pragma unroll
        for (int nt = 0; nt < 4; ++nt) acc[s][nt] = (f32x4){0.f, 0.f, 0.f, 0.f};

#define BPTR(slot, kk) (const bf16x8*)(Wb + ((size_t)((w + 4 * (slot)) * 20 + (kk)) << 10) + laneoff)
#define APTRX(nt, kk)  (const bf16x8*)(Xb + (((g0 + (nt)) * XKK + (kk)) << 10) + laneoff)
#define APTRH(nt, hc)  (const bf16x8*)(Hb + (((g0 + (nt)) * XKK + (hc)) << 10) + laneoff)
#define MFMA_ROW(s, Bv) \
    acc[s][0] = __builtin_amdgcn_mfma_f32_16x16x32_bf16(A0, Bv, acc[s][0], 0, 0, 0); \
    acc[s][1] = __builtin_amdgcn_mfma_f32_16x16x32_bf16(A1, Bv, acc[s][1], 0, 0, 0); \
    acc[s][2] = __builtin_amdgcn_mfma_f32_16x16x32_bf16(A2, Bv, acc[s][2], 0, 0, 0); \
    acc[s][3] = __builtin_amdgcn_mfma_f32_16x16x32_bf16(A3, Bv, acc[s][3], 0, 0, 0)

    // ---- Phase X: kk 0..11 (slots 0..5) ----
    for (int kk = 0; kk < XKK; ++kk) {
        bf16x8 A0 = *APTRX(0, kk), A1 = *APTRX(1, kk), A2 = *APTRX(2, kk), A3 = *APTRX(3, kk);
        bf16x8 B0 = *BPTR(0, kk), B1 = *BPTR(1, kk), B2 = *BPTR(2, kk),
               B3 = *BPTR(3, kk), B4 = *BPTR(4, kk), B5 = *BPTR(5, kk);
        MFMA_ROW(0, B0); MFMA_ROW(1, B1); MFMA_ROW(2, B2);
        MFMA_ROW(3, B3); MFMA_ROW(4, B4); MFMA_ROW(5, B5);
    }

    // ---- Phase H: hc 0..3 = W kk 16..19, A = bf16 mirror, slots {0,1,2,3,6,7} ----
    for (int hc = 0; hc < 4; ++hc) {
        const int kk = 16 + hc;
        bf16x8 A0 = *APTRH(0, hc), A1 = *APTRH(1, hc), A2 = *APTRH(2, hc), A3 = *APTRH(3, hc);
        bf16x8 B0 = *BPTR(0, kk), B1 = *BPTR(1, kk), B2 = *BPTR(2, kk),
               B3 = *BPTR(3, kk), B4 = *BPTR(6, kk), B5 = *BPTR(7, kk);
        MFMA_ROW(0, B0); MFMA_ROW(1, B1); MFMA_ROW(2, B2);
        MFMA_ROW(3, B3); MFMA_ROW(6, B4); MFMA_ROW(7, B5);
    }

    // ---- Phase ENC: ec 0..3 = W kk 12..15, A computed in-register, slots 0..5 ----
    for (int ec = 0; ec < 4; ++ec) {
        const int kk = 12 + ec;
        // issue B loads FIRST; cos/pack VALU below overlaps their latency
        bf16x8 B0 = *BPTR(0, kk), B1 = *BPTR(1, kk), B2 = *BPTR(2, kk),
               B3 = *BPTR(3, kk), B4 = *BPTR(4, kk), B5 = *BPTR(5, kk);
        const int f0 = ec * 32 + quad * 8;
        float wf[8];
#pragma unroll
        for (int j = 0; j < 8; ++j) wf[j] = __expf(-0.16317532f * (float)(f0 + j));
        bf16x8 A0, A1, A2, A3;
        {
            union { bf16x8 v; unsigned short u[8]; } r0, r1, r2, r3;
#pragma unroll
            for (int j = 0; j < 8; ++j) {
                r0.u[j] = f2bf(__cosf(dtv[0] * wf[j]));
                r1.u[j] = f2bf(__cosf(dtv[1] * wf[j]));
                r2.u[j] = f2bf(__cosf(dtv[2] * wf[j]));
                r3.u[j] = f2bf(__cosf(dtv[3] * wf[j]));
            }
            A0 = r0.v; A1 = r1.v; A2 = r2.v; A3 = r3.v;
        }
        MFMA_ROW(0, B0); MFMA_ROW(1, B1); MFMA_ROW(2, B2);
        MFMA_ROW(3, B3); MFMA_ROW(4, B4); MFMA_ROW(5, B5);
    }
#undef MFMA_ROW
#undef BPTR
#undef APTRX
#undef APTRH

    // ---- Epilogue (batched loads): lane owns node (g0+nt)*16 + quad*4 + reg,
    //      dims j = (w+4p)*16 + c ----
    const float* hsrc = (PASS == 0) ? memory : out_mem;

    int ebuf[4][4];
#pragma unroll
    for (int nt = 0; nt < 4; ++nt)
#pragma unroll
        for (int reg = 0; reg < 4; ++reg) {
            const long n = (g0 + nt) * 16 + quad * 4 + reg;
            ebuf[nt][reg] = (n < N_NODES_C) ? idxp[n] : -1;
        }

    float hbuf[2][4][4];
#pragma unroll
    for (int p = 0; p < 2; ++p) {
        const int j = (w + 4 * p) * 16 + c;
#pragma unroll
        for (int nt = 0; nt < 4; ++nt)
#pragma unroll
            for (int reg = 0; reg < 4; ++reg) {
                const long n = (g0 + nt) * 16 + quad * 4 + reg;
                hbuf[p][nt][reg] = hsrc[(size_t)(n < N_NODES_C ? n : 0) * DIM_C + j];
            }
    }

#pragma unroll
    for (int p = 0; p < 2; ++p) {
        const int j = (w + 4 * p) * 16 + c;
        const float br = b_ih[j] + b_hh[j];
        const float bz = b_ih[128 + j] + b_hh[128 + j];
        const float bi = b_ih[256 + j];
        const float bh = b_hh[256 + j];
        // bf16-mirror address components for dim j (A-frag layout within self block)
        const int kkm = j >> 5;
        const int q2  = (j >> 3) & 3;
        const int bb  = j & 7;
#pragma unroll
        for (int nt = 0; nt < 4; ++nt) {
#pragma unroll
            for (int reg = 0; reg < 4; ++reg) {
                const long n = (g0 + nt) * 16 + quad * 4 + reg;
                if (n < N_NODES_C && ebuf[nt][reg] >= 0) {
                    const float r  = sigmoidf_(acc[0 + p][nt][reg] + br);
                    const float z  = sigmoidf_(acc[2 + p][nt][reg] + bz);
                    const float nn = tanhf_(acc[4 + p][nt][reg] + bi + r * (acc[6 + p][nt][reg] + bh));
                    const float h  = hbuf[p][nt][reg];
                    const float hnew = (1.0f - z) * nn + z * h;
                    out_mem[(size_t)n * DIM_C + j] = hnew;
                    if (PASS == 0) {
                        const int row = quad * 4 + reg;
                        *(unsigned short*)((char*)Hmir + (((g0 + nt) * XKK + kkm) << 10)
                                           + ((q2 * 16 + row) << 4) + (bb << 1)) = f2bf(hnew);
                    }
                }
            }
        }
    }
}

// =====================  FALLBACK (R2 fused) PATH  =====================
#define NODES_PB  32
#define LDSW      648
#define WROWS     512
#define NXF       640

__global__ void build_wall_kernel(const float* __restrict__ W_ih, const float* __restrict__ W_hh,
                                  unsigned short* __restrict__ Wall) {
    int i = blockIdx.x * 256 + threadIdx.x;
    if (i >= WROWS * NXF) return;
    int r = i / NXF, k = i - r * NXF;
    float v;
    if (r < 256)      v = (k < 512) ? W_ih[(long)r * DMSG_C + k] : W_hh[(long)r * DIM_C + (k - 512)];
    else if (r < 384) v = (k < 512) ? W_ih[(long)r * DMSG_C + k] : 0.0f;
    else              v = (k >= 512) ? W_hh[(long)(r - 128) * DIM_C + (k - 512)] : 0.0f;
    Wall[i] = f2bf(v);
}

template <int PASS>
__global__ __launch_bounds__(256) void gru_mfma_kernel(
    const float* __restrict__ memory, const float* __restrict__ last_update,
    const unsigned short* __restrict__ Wall,
    const float* __restrict__ b_ih, const float* __restrict__ b_hh,
    const float* __restrict__ edge_times, const float* __restrict__ edge_feat,
    const int* __restrict__ src, const int* __restrict__ dst,
    const int* __restrict__ idx,
    float* __restrict__ out_mem, float* __restrict__ out_lu)
{
    __shared__ __align__(16) unsigned short Xl[NODES_PB][LDSW];
    __shared__ int eidx[NODES_PB];
    const int t = threadIdx.x;
    const int base = blockIdx.x * NODES_PB;
    if (t < NODES_PB) eidx[t] = idx[base + t];
    __syncthreads();
    const int tt = t & 127;
    const int sh = t >> 7;
    const float wfreq = __expf(-0.16317532f * (float)tt);
    for (int s0 = 0; s0 < NODES_PB; s0 += 2) {
        const int s = s0 + sh;
        const int n = base + s;
        const int e = eidx[s];
        const int eu = (e >= 0) ? e : 0;
        const int other = (PASS == 0) ? dst[eu] : src[eu];
        const float mself = memory[(long)n * DIM_C + tt];
        const float moth  = memory[(long)other * DIM_C + tt];
        const float ef    = edge_feat[(long)eu * DIM_C + tt];
        const float dt    = edge_times[eu] - last_update[n];
        const float enc   = __cosf(dt * wfreq);
        const float hv    = (PASS == 0) ? mself : out_mem[(long)n * DIM_C + tt];
        Xl[s][tt]       = f2bf(mself);
        Xl[s][128 + tt] = f2bf(moth);
        Xl[s][256 + tt] = f2bf(ef);
        Xl[s][384 + tt] = f2bf(enc);
        Xl[s][512 + tt] = f2bf(hv);
    }
    __syncthreads();
    const int w = t >> 6, lane = t & 63;
    const int quad = lane >> 4, c = lane & 15;
    f32x4 acc[8][2];
#pragma unroll
    for (int i = 0; i < 8; ++i)
#pragma unroll
        for (int mt = 0; mt < 2; ++mt) acc[i][mt] = (f32x4){0.f, 0.f, 0.f, 0.f};
    const unsigned short* wrow[8];
#pragma unroll
    for (int i = 0; i < 8; ++i)
        wrow[i] = Wall + (long)((w + 4 * i) * 16 + c) * NXF + quad * 8;
    for (int kk = 0; kk < 16; ++kk) {
        const int k0 = kk * 32;
        bf16x8 a0 = *(const bf16x8*)&Xl[c][k0 + quad * 8];
        bf16x8 a1 = *(const bf16x8*)&Xl[16 + c][k0 + quad * 8];
#pragma unroll
        for (int i = 0; i < 6; ++i) {
            bf16x8 b = *(const bf16x8*)(wrow[i] + k0);
            acc[i][0] = __builtin_amdgcn_mfma_f32_16x16x32_bf16(a0, b, acc[i][0], 0, 0, 0);
            acc[i][1] = __builtin_amdgcn_mfma_f32_16x16x32_bf16(a1, b, acc[i][1], 0, 0, 0);
        }
    }
    for (int kk = 16; kk < 20; ++kk) {
        const int k0 = kk * 32;
        bf16x8 a0 = *(const bf16x8*)&Xl[c][k0 + quad * 8];
        bf16x8 a1 = *(const bf16x8*)&Xl[16 + c][k0 + quad * 8];
#pragma unroll
        for (int ii = 0; ii < 6; ++ii) {
            const int i = (ii < 4) ? ii : ii + 2;
            bf16x8 b = *(const bf16x8*)(wrow[i] + k0);
            acc[i][0] = __builtin_amdgcn_mfma_f32_16x16x32_bf16(a0, b, acc[i][0], 0, 0, 0);
            acc[i][1] = __builtin_amdgcn_mfma_f32_16x16x32_bf16(a1, b, acc[i][1], 0, 0, 0);
        }
    }
    const float* hsrc = (PASS == 0) ? memory : out_mem;
#pragma unroll
    for (int p = 0; p < 2; ++p) {
        const int j = (w + 4 * p) * 16 + c;
        const float br = b_ih[j] + b_hh[j];
        const float bz = b_ih[128 + j] + b_hh[128 + j];
        const float bi = b_ih[256 + j];
        const float bh = b_hh[256 + j];
#pragma unroll
        for (int mt = 0; mt < 2; ++mt) {
#pragma unroll
            for (int reg = 0; reg < 4; ++reg) {
                const int ml = mt * 16 + quad * 4 + reg;
                const int n = base + ml;
                const int e = eidx[ml];
                const float h = hsrc[(long)n * DIM_C + j];
                if (e >= 0) {
                    const float r  = sigmoidf_(acc[p][mt][reg] + br);
                    const float z  = sigmoidf_(acc[p + 2][mt][reg] + bz);
                    const float nn = tanhf_(acc[p + 4][mt][reg] + bi + r * (acc[p + 6][mt][reg] + bh));
                    out_mem[(long)n * DIM_C + j] = (1.0f - z) * nn + z * h;
                } else if (PASS == 0) {
                    out_mem[(long)n * DIM_C + j] = h;
                }
            }
        }
    }
    if (t < NODES_PB) {
        const int n = base + t;
        const int e = eidx[t];
        if (e >= 0)         out_lu[n] = edge_times[e];
        else if (PASS == 0) out_lu[n] = last_update[n];
    }
}

// =====================  LAUNCH  =====================
extern "C" void kernel_launch(void* const* d_in, const int* in_sizes, int n_in,
                              void* d_out, int out_size, void* d_ws, size_t ws_size,
                              hipStream_t stream) {
    const float* memory      = (const float*)d_in[0];
    const float* last_update = (const float*)d_in[1];
    const float* W_ih        = (const float*)d_in[2];
    const float* W_hh        = (const float*)d_in[3];
    const float* b_ih        = (const float*)d_in[4];
    const float* b_hh        = (const float*)d_in[5];
    const float* edge_times  = (const float*)d_in[6];
    const float* edge_feat   = (const float*)d_in[7];
    const int*   src         = (const int*)d_in[8];
    const int*   dst         = (const int*)d_in[9];

    float* out_mem = (float*)d_out;
    float* out_lu  = out_mem + (size_t)N_NODES_C * DIM_C;

    // ws layout (main path)
    const size_t sIdx  = (size_t)NODES_PAD * 4;           // 400128 B each
    const size_t sDt   = (size_t)NODES_PAD * 4;
    const size_t sWall = (size_t)32 * 20 * 1024;          // 655360 B
    const size_t sX    = (size_t)GROUPS_PAD * XKK * 1024; // 76.8 MB each
    const size_t oIdxS = 0, oIdxD = oIdxS + sIdx, oDtS = oIdxD + sIdx, oDtD = oDtS + sDt;
    const size_t oWall = oDtD + sDt, oXs = oWall + sWall, oXd = oXs + sX;
    const size_t need  = oXd + sX;                        // ~149 MB

    if (ws_size >= need) {
        int* idx_s = (int*)((char*)d_ws + oIdxS);
        int* idx_d = (int*)((char*)d_ws + oIdxD);
        float* dt_s = (float*)((char*)d_ws + oDtS);
        float* dt_d = (float*)((char*)d_ws + oDtD);
        unsigned short* Wsw = (unsigned short*)((char*)d_ws + oWall);
        unsigned short* Xs  = (unsigned short*)((char*)d_ws + oXs);
        unsigned short* Xd  = (unsigned short*)((char*)d_ws + oXd);

        hipMemsetAsync(d_ws, 0xFF, 2 * sIdx, stream);     // idx arrays = -1
        scatter_last_kernel<<<(N_EDGES_C + 255) / 256, 256, 0, stream>>>(src, dst, idx_s, idx_d);
        build_wallsw_kernel<<<160, 256, 0, stream>>>(W_ih, W_hh, Wsw);
        gather_kernel<<<N_NODES_C / 16, 256, 0, stream>>>(
            memory, last_update, edge_times, edge_feat, src, dst,
            idx_s, idx_d, dt_s, dt_d, Xs, Xd, out_mem, out_lu);
        gemm_pass_kernel<0><<<GROUPS_PAD / 4, 256, 0, stream>>>(
            memory, Wsw, b_ih, b_hh, Xs, Xs, dt_s, idx_s, out_mem);
        gemm_pass_kernel<1><<<GROUPS_PAD / 4, 256, 0, stream>>>(
            memory, Wsw, b_ih, b_hh, Xd, Xs, dt_d, idx_d, out_mem);
    } else {
        // R2 fused fallback (needs ~1.5 MB ws)
        int* idx_s = (int*)d_ws;
        int* idx_d = idx_s + N_NODES_C;
        unsigned short* Wall = (unsigned short*)((char*)d_ws + 2 * N_NODES_C * sizeof(int));
        hipMemsetAsync(d_ws, 0xFF, 2 * N_NODES_C * sizeof(int), stream);
        scatter_last_kernel<<<(N_EDGES_C + 255) / 256, 256, 0, stream>>>(src, dst, idx_s, idx_d);
        build_wall_kernel<<<(WROWS * NXF + 255) / 256, 256, 0, stream>>>(W_ih, W_hh, Wall);
        gru_mfma_kernel<0><<<N_NODES_C / NODES_PB, 256, 0, stream>>>(
            memory, last_update, Wall, b_ih, b_hh, edge_times, edge_feat,
            src, dst, idx_s, out_mem, out_lu);
        gru_mfma_kernel<1><<<N_NODES_C / NODES_PB, 256, 0, stream>>>(
            memory, last_update, Wall, b_ih, b_hh, edge_times, edge_feat,
            src, dst, idx_d, out_mem, out_lu);
    }
}

// Round 5
// 485.348 us; speedup vs baseline: 1.3650x; 1.0216x over previous
//
#include <hip/hip_runtime.h>
#include <math.h>

// Problem constants (match reference file)
#define N_NODES_C 100000
#define DIM_C     128
#define DMSG_C    512
#define N_EDGES_C 200000

// GEMM geometry: 64 nodes/block (4 node-groups of 16), 512 gate rows = 32 tiles
#define GROUPS_PAD 6252            // 1563 blocks * 4 groups
#define NODES_PAD  (GROUPS_PAD*16) // 100032
#define XKK 12                     // X = [self|other|ef] = 384 cols = 12 kk-chunks of 32

typedef __attribute__((ext_vector_type(8))) __bf16 bf16x8;
typedef __attribute__((ext_vector_type(4))) float  f32x4;

__device__ __forceinline__ float sigmoidf_(float x) { return 1.0f / (1.0f + __expf(-x)); }
// fast tanh: 1 - 2/(e^{2x}+1); exact at +/-inf, ~1e-7 abs err mid-range (<< bf16 gemm noise)
__device__ __forceinline__ float tanhf_(float x) { return 1.0f - 2.0f / (__expf(2.0f * x) + 1.0f); }
__device__ __forceinline__ unsigned short f2bf(float x) {
    union { float f; unsigned u; } v; v.f = x;
    unsigned r = v.u + 0x7FFFu + ((v.u >> 16) & 1u);   // RNE
    return (unsigned short)(r >> 16);
}
__device__ __forceinline__ void st8(void* p, float4 lo, float4 hi) {
    union { bf16x8 v; unsigned short u[8]; } r;
    r.u[0] = f2bf(lo.x); r.u[1] = f2bf(lo.y); r.u[2] = f2bf(lo.z); r.u[3] = f2bf(lo.w);
    r.u[4] = f2bf(hi.x); r.u[5] = f2bf(hi.y); r.u[6] = f2bf(hi.z); r.u[7] = f2bf(hi.w);
    *(bf16x8*)p = r.v;
}

// ---- last occurrence of each node in edge order ----
__global__ void scatter_last_kernel(const int* __restrict__ src, const int* __restrict__ dst,
                                    int* __restrict__ idx_s, int* __restrict__ idx_d) {
    int e = blockIdx.x * blockDim.x + threadIdx.x;
    if (e < N_EDGES_C) {
        atomicMax(&idx_s[src[e]], e);
        atomicMax(&idx_d[dst[e]], e);
    }
}

// =====================  MAIN (split) PATH  =====================
// Wsw[tile][kk][lane][8]: B-fragment order. tile T: packed gate rows T*16+(l&15):
//   rows 0..127 r, 128..255 z, 256..383 i_n (W_ih), 384..511 h_n (W_hh rows 256..383)
// K map: 0..127 self, 128..255 other, 256..383 ef, 384..511 enc, 512..639 h
__global__ void build_wallsw_kernel(const float* __restrict__ W_ih, const float* __restrict__ W_hh,
                                    unsigned short* __restrict__ Wsw) {
    int id = blockIdx.x * 256 + threadIdx.x;           // 32*20*64 = 40960
    if (id >= 32 * 20 * 64) return;
    int tile = id / 1280, r = id - tile * 1280, kk = r >> 6, l = r & 63;
    int pr = tile * 16 + (l & 15);
    int k0 = kk * 32 + ((l >> 4) & 3) * 8;
    float v[8];
#pragma unroll
    for (int j = 0; j < 8; ++j) {
        int k = k0 + j;
        if (pr < 256)      v[j] = (k < 512) ? W_ih[(long)pr * DMSG_C + k] : W_hh[(long)pr * DIM_C + (k - 512)];
        else if (pr < 384) v[j] = (k < 512) ? W_ih[(long)pr * DMSG_C + k] : 0.0f;
        else               v[j] = (k >= 512) ? W_hh[(long)(pr - 128) * DIM_C + (k - 512)] : 0.0f;
    }
    union { bf16x8 bv; unsigned short u[8]; } o;
#pragma unroll
    for (int j = 0; j < 8; ++j) o.u[j] = f2bf(v[j]);
    *(bf16x8*)((char*)Wsw + ((size_t)(tile * 20 + kk) << 10) + ((size_t)l << 4)) = o.bv;
}

// Gather: 16 nodes/block. Builds Xs/Xd (A-frag-swizzled bf16), dt arrays, out_lu,
// and the inactive-pass0 copy of memory into out_mem.
__global__ __launch_bounds__(256) void gather_kernel(
    const float* __restrict__ memory, const float* __restrict__ last_update,
    const float* __restrict__ edge_times, const float* __restrict__ edge_feat,
    const int* __restrict__ src, const int* __restrict__ dst,
    const int* __restrict__ idx_s, const int* __restrict__ idx_d,
    float* __restrict__ dt_s, float* __restrict__ dt_d,
    unsigned short* __restrict__ Xs, unsigned short* __restrict__ Xd,
    float* __restrict__ out_mem, float* __restrict__ out_lu)
{
    __shared__ int es_l[16], ed_l[16], os_l[16], od_l[16];
    const int t = threadIdx.x;
    const int base = blockIdx.x * 16;
    if (t < 16) {
        const int n = base + t;
        const int es = idx_s[n], ed = idx_d[n];
        const int eus = es < 0 ? 0 : es, eud = ed < 0 ? 0 : ed;
        es_l[t] = es; ed_l[t] = ed;
        os_l[t] = dst[eus]; od_l[t] = src[eud];
        const float lun = last_update[n];
        const float ts = edge_times[eus], td = edge_times[eud];
        dt_s[n] = ts - lun; dt_d[n] = td - lun;
        out_lu[n] = (ed >= 0) ? td : ((es >= 0) ? ts : lun);
    }
    __syncthreads();
    const int m = t & 15, q = t >> 4;                  // node-in-block, col-chunk (8 cols)
    const int n = base + m;
    const size_t g = blockIdx.x;                       // node-group == block
    const int es = es_l[m];
    const int eus = (es < 0) ? 0 : es;
    const int eud = (ed_l[m] < 0) ? 0 : ed_l[m];
    const float4* self_p = (const float4*)(memory + (size_t)n * DIM_C + q * 8);
    const float4* oS_p   = (const float4*)(memory + (size_t)os_l[m] * DIM_C + q * 8);
    const float4* oD_p   = (const float4*)(memory + (size_t)od_l[m] * DIM_C + q * 8);
    const float4* eS_p   = (const float4*)(edge_feat + (size_t)eus * DIM_C + q * 8);
    const float4* eD_p   = (const float4*)(edge_feat + (size_t)eud * DIM_C + q * 8);
    float4 s0 = self_p[0], s1 = self_p[1];
    float4 a0 = oS_p[0],   a1 = oS_p[1];
    float4 b0 = oD_p[0],   b1 = oD_p[1];
    float4 c0 = eS_p[0],   c1 = eS_p[1];
    float4 d0 = eD_p[0],   d1 = eD_p[1];
    const int kkq = q >> 2;
    const size_t laneoff = (size_t)(((q & 3) * 16 + m)) << 4;
    char* XsB = (char*)Xs; char* XdB = (char*)Xd;
#define XOFF(kk) ((((g * XKK) + (kk)) << 10) + laneoff)
    st8(XsB + XOFF(kkq),     s0, s1);
    st8(XsB + XOFF(4 + kkq), a0, a1);
    st8(XsB + XOFF(8 + kkq), c0, c1);
    st8(XdB + XOFF(kkq),     s0, s1);
    st8(XdB + XOFF(4 + kkq), b0, b1);
    st8(XdB + XOFF(8 + kkq), d0, d1);
#undef XOFF
    if (es < 0) {   // inactive in pass0: seed out_mem with original memory row
        float4* op = (float4*)(out_mem + (size_t)n * DIM_C + q * 8);
        op[0] = s0; op[1] = s1;
    }
}

// GEMM+GRU pass, R7: LDS double-buffered global_load_lds pipeline (guide's
// minimal 2-phase template). 256 thr = 4 waves over 64 nodes; wave w owns
// gate-tiles {w,w+4,...,w+28} = slots {r0,r1,z0,z1,i0,i1,h0,h1}.
//
// R6 post-mortem: batched register loads removed only 1 of ~4 latency
// exposures/iter — 244/256 regs/wave means the allocator can't keep 10
// loads (40 landing VGPRs) in flight. global_load_lds needs ZERO landing
// registers; the vmcnt(0) drain inside __syncthreads is issued AFTER the
// MFMA cluster, so stage latency is covered by compute + cross-block TLP
// (2 blocks/CU).
//
// LDS (56 KB, double-buffered 28 KB):  A: [cur][nt][1KB]  B: [cur][w][s6][1KB]
// Per iter wave w stages its group-w A tile + its 6 B tiles (7 gload_lds).
// Step order: st 0..11 X (slots 0..5), st 12..15 H mirror (W kk 16..19,
// slots {0,1,2,3,6,7}), st 16..19 ENC in-register (W kk 12..15, slots 0..5).
template <int PASS>
__global__ __launch_bounds__(256, 2) void gemm_pass_kernel(
    const float* __restrict__ memory,
    const unsigned short* __restrict__ Wsw,
    const float* __restrict__ b_ih, const float* __restrict__ b_hh,
    const unsigned short* __restrict__ Xsw,
    unsigned short* Hmir,                      // = Xs (self-block mirror; aliases Xsw in pass0)
    const float* __restrict__ dtp, const int* __restrict__ idxp,
    float* __restrict__ out_mem)
{
    __shared__ __align__(1024) char lds[57344];
    const int t = threadIdx.x;
    const int w = t >> 6, lane = t & 63, quad = lane >> 4, c = lane & 15;
    const long g0 = (long)blockIdx.x * 4;
    const char* Xb = (const char*)Xsw;
    const char* Hb = (const char*)Hmir;
    const char* Wb = (const char*)Wsw;
    const size_t laneoff = (size_t)lane << 4;

#define ABUF(cur, nt)     ((((cur) * 28) + (nt)) << 10)
#define BBUF(cur, wv, s6) ((((cur) * 28) + 4 + (wv) * 6 + (s6)) << 10)

    // dt values (batched early; used in ENC steps)
    float dtv[4];
#pragma unroll
    for (int nt = 0; nt < 4; ++nt) dtv[nt] = dtp[(g0 + nt) * 16 + c];

    auto stage = [&](const char* gsrc, int ldsoff) {
        __builtin_amdgcn_global_load_lds(
            (const __attribute__((address_space(1))) void*)(gsrc + laneoff),
            (__attribute__((address_space(3))) void*)(lds + ldsoff), 16, 0, 0);
    };
    auto kk_of = [](int st) { return (st < 12) ? st : ((st < 16) ? st + 4 : st - 4); };
    auto slot_of = [](int st, int s6) {
        return (st >= 12 && st < 16) ? ((s6 < 4) ? s6 : s6 + 2) : s6;
    };
    // wave w stages: its group's A tile (st<16) + its own 6 B tiles
    auto stage_step = [&](int st, int cur) {
        if (st < 16) {
            const char* asrc = (st < 12)
                ? (Xb + (((g0 + w) * XKK + st) << 10))
                : (Hb + (((g0 + w) * XKK + (st - 12)) << 10));
            stage(asrc, ABUF(cur, w));
        }
        const int kk = kk_of(st);
#pragma unroll
        for (int s6 = 0; s6 < 6; ++s6)
            stage(Wb + ((size_t)((w + 4 * slot_of(st, s6)) * 20 + kk) << 10),
                  BBUF(cur, w, s6));
    };

    f32x4 acc[8][4];
#pragma unroll
    for (int s = 0; s < 8; ++s)
#pragma unroll
        for (int nt = 0; nt < 4; ++nt) acc[s][nt] = (f32x4){0.f, 0.f, 0.f, 0.f};

#define MFMA_ROW(s, Bv) \
    acc[s][0] = __builtin_amdgcn_mfma_f32_16x16x32_bf16(A0, Bv, acc[s][0], 0, 0, 0); \
    acc[s][1] = __builtin_amdgcn_mfma_f32_16x16x32_bf16(A1, Bv, acc[s][1], 0, 0, 0); \
    acc[s][2] = __builtin_amdgcn_mfma_f32_16x16x32_bf16(A2, Bv, acc[s][2], 0, 0, 0); \
    acc[s][3] = __builtin_amdgcn_mfma_f32_16x16x32_bf16(A3, Bv, acc[s][3], 0, 0, 0)

    stage_step(0, 0);
    __syncthreads();   // drain prologue stage

#pragma unroll
    for (int st = 0; st < 20; ++st) {
        const int cur = st & 1;
        if (st < 19) stage_step(st + 1, cur ^ 1);   // issue next-step DMA first

        bf16x8 A0, A1, A2, A3;
        if (st < 16) {
            A0 = *(const bf16x8*)(lds + ABUF(cur, 0) + laneoff);
            A1 = *(const bf16x8*)(lds + ABUF(cur, 1) + laneoff);
            A2 = *(const bf16x8*)(lds + ABUF(cur, 2) + laneoff);
            A3 = *(const bf16x8*)(lds + ABUF(cur, 3) + laneoff);
        } else {
            // ENC: A = cos(dt * w_f) computed in-register (overlaps B DMA)
            const int ec = st - 16;
            const int f0 = ec * 32 + quad * 8;
            float wf[8];
#pragma unroll
            for (int j = 0; j < 8; ++j) wf[j] = __expf(-0.16317532f * (float)(f0 + j));
            union { bf16x8 v; unsigned short u[8]; } r0, r1, r2, r3;
#pragma unroll
            for (int j = 0; j < 8; ++j) {
                r0.u[j] = f2bf(__cosf(dtv[0] * wf[j]));
                r1.u[j] = f2bf(__cosf(dtv[1] * wf[j]));
                r2.u[j] = f2bf(__cosf(dtv[2] * wf[j]));
                r3.u[j] = f2bf(__cosf(dtv[3] * wf[j]));
            }
            A0 = r0.v; A1 = r1.v; A2 = r2.v; A3 = r3.v;
        }
        bf16x8 B0 = *(const bf16x8*)(lds + BBUF(cur, w, 0) + laneoff);
        bf16x8 B1 = *(const bf16x8*)(lds + BBUF(cur, w, 1) + laneoff);
        bf16x8 B2 = *(const bf16x8*)(lds + BBUF(cur, w, 2) + laneoff);
        bf16x8 B3 = *(const bf16x8*)(lds + BBUF(cur, w, 3) + laneoff);
        bf16x8 B4 = *(const bf16x8*)(lds + BBUF(cur, w, 4) + laneoff);
        bf16x8 B5 = *(const bf16x8*)(lds + BBUF(cur, w, 5) + laneoff);

        __builtin_amdgcn_s_setprio(1);
        if (st >= 12 && st < 16) {
            MFMA_ROW(0, B0); MFMA_ROW(1, B1); MFMA_ROW(2, B2);
            MFMA_ROW(3, B3); MFMA_ROW(6, B4); MFMA_ROW(7, B5);
        } else {
            MFMA_ROW(0, B0); MFMA_ROW(1, B1); MFMA_ROW(2, B2);
            MFMA_ROW(3, B3); MFMA_ROW(4, B4); MFMA_ROW(5, B5);
        }
        __builtin_amdgcn_s_setprio(0);

        if (st < 19) __syncthreads();   // vmcnt(0) drain: next-step stage landed
    }
#undef MFMA_ROW
#undef ABUF
#undef BBUF

    // ---- Epilogue (batched loads): lane owns node (g0+nt)*16 + quad*4 + reg,
    //      dims j = (w+4p)*16 + c ----
    const float* hsrc = (PASS == 0) ? memory : out_mem;

    int ebuf[4][4];
#pragma unroll
    for (int nt = 0; nt < 4; ++nt)
#pragma unroll
        for (int reg = 0; reg < 4; ++reg) {
            const long n = (g0 + nt) * 16 + quad * 4 + reg;
            ebuf[nt][reg] = (n < N_NODES_C) ? idxp[n] : -1;
        }

    float hbuf[2][4][4];
#pragma unroll
    for (int p = 0; p < 2; ++p) {
        const int j = (w + 4 * p) * 16 + c;
#pragma unroll
        for (int nt = 0; nt < 4; ++nt)
#pragma unroll
            for (int reg = 0; reg < 4; ++reg) {
                const long n = (g0 + nt) * 16 + quad * 4 + reg;
                hbuf[p][nt][reg] = hsrc[(size_t)(n < N_NODES_C ? n : 0) * DIM_C + j];
            }
    }

#pragma unroll
    for (int p = 0; p < 2; ++p) {
        const int j = (w + 4 * p) * 16 + c;
        const float br = b_ih[j] + b_hh[j];
        const float bz = b_ih[128 + j] + b_hh[128 + j];
        const float bi = b_ih[256 + j];
        const float bh = b_hh[256 + j];
        // bf16-mirror address components for dim j (A-frag layout within self block)
        const int kkm = j >> 5;
        const int q2  = (j >> 3) & 3;
        const int bb  = j & 7;
#pragma unroll
        for (int nt = 0; nt < 4; ++nt) {
#pragma unroll
            for (int reg = 0; reg < 4; ++reg) {
                const long n = (g0 + nt) * 16 + quad * 4 + reg;
                if (n < N_NODES_C && ebuf[nt][reg] >= 0) {
                    const float r  = sigmoidf_(acc[0 + p][nt][reg] + br);
                    const float z  = sigmoidf_(acc[2 + p][nt][reg] + bz);
                    const float nn = tanhf_(acc[4 + p][nt][reg] + bi + r * (acc[6 + p][nt][reg] + bh));
                    const float h  = hbuf[p][nt][reg];
                    const float hnew = (1.0f - z) * nn + z * h;
                    out_mem[(size_t)n * DIM_C + j] = hnew;
                    if (PASS == 0) {
                        const int row = quad * 4 + reg;
                        *(unsigned short*)((char*)Hmir + (((g0 + nt) * XKK + kkm) << 10)
                                           + ((q2 * 16 + row) << 4) + (bb << 1)) = f2bf(hnew);
                    }
                }
            }
        }
    }
}

// =====================  FALLBACK (R2 fused) PATH  =====================
#define NODES_PB  32
#define LDSW      648
#define WROWS     512
#define NXF       640

__global__ void build_wall_kernel(const float* __restrict__ W_ih, const float* __restrict__ W_hh,
                                  unsigned short* __restrict__ Wall) {
    int i = blockIdx.x * 256 + threadIdx.x;
    if (i >= WROWS * NXF) return;
    int r = i / NXF, k = i - r * NXF;
    float v;
    if (r < 256)      v = (k < 512) ? W_ih[(long)r * DMSG_C + k] : W_hh[(long)r * DIM_C + (k - 512)];
    else if (r < 384) v = (k < 512) ? W_ih[(long)r * DMSG_C + k] : 0.0f;
    else              v = (k >= 512) ? W_hh[(long)(r - 128) * DIM_C + (k - 512)] : 0.0f;
    Wall[i] = f2bf(v);
}

template <int PASS>
__global__ __launch_bounds__(256) void gru_mfma_kernel(
    const float* __restrict__ memory, const float* __restrict__ last_update,
    const unsigned short* __restrict__ Wall,
    const float* __restrict__ b_ih, const float* __restrict__ b_hh,
    const float* __restrict__ edge_times, const float* __restrict__ edge_feat,
    const int* __restrict__ src, const int* __restrict__ dst,
    const int* __restrict__ idx,
    float* __restrict__ out_mem, float* __restrict__ out_lu)
{
    __shared__ __align__(16) unsigned short Xl[NODES_PB][LDSW];
    __shared__ int eidx[NODES_PB];
    const int t = threadIdx.x;
    const int base = blockIdx.x * NODES_PB;
    if (t < NODES_PB) eidx[t] = idx[base + t];
    __syncthreads();
    const int tt = t & 127;
    const int sh = t >> 7;
    const float wfreq = __expf(-0.16317532f * (float)tt);
    for (int s0 = 0; s0 < NODES_PB; s0 += 2) {
        const int s = s0 + sh;
        const int n = base + s;
        const int e = eidx[s];
        const int eu = (e >= 0) ? e : 0;
        const int other = (PASS == 0) ? dst[eu] : src[eu];
        const float mself = memory[(long)n * DIM_C + tt];
        const float moth  = memory[(long)other * DIM_C + tt];
        const float ef    = edge_feat[(long)eu * DIM_C + tt];
        const float dt    = edge_times[eu] - last_update[n];
        const float enc   = __cosf(dt * wfreq);
        const float hv    = (PASS == 0) ? mself : out_mem[(long)n * DIM_C + tt];
        Xl[s][tt]       = f2bf(mself);
        Xl[s][128 + tt] = f2bf(moth);
        Xl[s][256 + tt] = f2bf(ef);
        Xl[s][384 + tt] = f2bf(enc);
        Xl[s][512 + tt] = f2bf(hv);
    }
    __syncthreads();
    const int w = t >> 6, lane = t & 63;
    const int quad = lane >> 4, c = lane & 15;
    f32x4 acc[8][2];
#pragma unroll
    for (int i = 0; i < 8; ++i)
#pragma unroll
        for (int mt = 0; mt < 2; ++mt) acc[i][mt] = (f32x4){0.f, 0.f, 0.f, 0.f};
    const unsigned short* wrow[8];
#pragma unroll
    for (int i = 0; i < 8; ++i)
        wrow[i] = Wall + (long)((w + 4 * i) * 16 + c) * NXF + quad * 8;
    for (int kk = 0; kk < 16; ++kk) {
        const int k0 = kk * 32;
        bf16x8 a0 = *(const bf16x8*)&Xl[c][k0 + quad * 8];
        bf16x8 a1 = *(const bf16x8*)&Xl[16 + c][k0 + quad * 8];
#pragma unroll
        for (int i = 0; i < 6; ++i) {
            bf16x8 b = *(const bf16x8*)(wrow[i] + k0);
            acc[i][0] = __builtin_amdgcn_mfma_f32_16x16x32_bf16(a0, b, acc[i][0], 0, 0, 0);
            acc[i][1] = __builtin_amdgcn_mfma_f32_16x16x32_bf16(a1, b, acc[i][1], 0, 0, 0);
        }
    }
    for (int kk = 16; kk < 20; ++kk) {
        const int k0 = kk * 32;
        bf16x8 a0 = *(const bf16x8*)&Xl[c][k0 + quad * 8];
        bf16x8 a1 = *(const bf16x8*)&Xl[16 + c][k0 + quad * 8];
#pragma unroll
        for (int ii = 0; ii < 6; ++ii) {
            const int i = (ii < 4) ? ii : ii + 2;
            bf16x8 b = *(const bf16x8*)(wrow[i] + k0);
            acc[i][0] = __builtin_amdgcn_mfma_f32_16x16x32_bf16(a0, b, acc[i][0], 0, 0, 0);
            acc[i][1] = __builtin_amdgcn_mfma_f32_16x16x32_bf16(a1, b, acc[i][1], 0, 0, 0);
        }
    }
    const float* hsrc = (PASS == 0) ? memory : out_mem;
#pragma unroll
    for (int p = 0; p < 2; ++p) {
        const int j = (w + 4 * p) * 16 + c;
        const float br = b_ih[j] + b_hh[j];
        const float bz = b_ih[128 + j] + b_hh[128 + j];
        const float bi = b_ih[256 + j];
        const float bh = b_hh[256 + j];
#pragma unroll
        for (int mt = 0; mt < 2; ++mt) {
#pragma unroll
            for (int reg = 0; reg < 4; ++reg) {
                const int ml = mt * 16 + quad * 4 + reg;
                const int n = base + ml;
                const int e = eidx[ml];
                const float h = hsrc[(long)n * DIM_C + j];
                if (e >= 0) {
                    const float r  = sigmoidf_(acc[p][mt][reg] + br);
                    const float z  = sigmoidf_(acc[p + 2][mt][reg] + bz);
                    const float nn = tanhf_(acc[p + 4][mt][reg] + bi + r * (acc[p + 6][mt][reg] + bh));
                    out_mem[(long)n * DIM_C + j] = (1.0f - z) * nn + z * h;
                } else if (PASS == 0) {
                    out_mem[(long)n * DIM_C + j] = h;
                }
            }
        }
    }
    if (t < NODES_PB) {
        const int n = base + t;
        const int e = eidx[t];
        if (e >= 0)         out_lu[n] = edge_times[e];
        else if (PASS == 0) out_lu[n] = last_update[n];
    }
}

// =====================  LAUNCH  =====================
extern "C" void kernel_launch(void* const* d_in, const int* in_sizes, int n_in,
                              void* d_out, int out_size, void* d_ws, size_t ws_size,
                              hipStream_t stream) {
    const float* memory      = (const float*)d_in[0];
    const float* last_update = (const float*)d_in[1];
    const float* W_ih        = (const float*)d_in[2];
    const float* W_hh        = (const float*)d_in[3];
    const float* b_ih        = (const float*)d_in[4];
    const float* b_hh        = (const float*)d_in[5];
    const float* edge_times  = (const float*)d_in[6];
    const float* edge_feat   = (const float*)d_in[7];
    const int*   src         = (const int*)d_in[8];
    const int*   dst         = (const int*)d_in[9];

    float* out_mem = (float*)d_out;
    float* out_lu  = out_mem + (size_t)N_NODES_C * DIM_C;

    // ws layout (main path)
    const size_t sIdx  = (size_t)NODES_PAD * 4;           // 400128 B each
    const size_t sDt   = (size_t)NODES_PAD * 4;
    const size_t sWall = (size_t)32 * 20 * 1024;          // 655360 B
    const size_t sX    = (size_t)GROUPS_PAD * XKK * 1024; // 76.8 MB each
    const size_t oIdxS = 0, oIdxD = oIdxS + sIdx, oDtS = oIdxD + sIdx, oDtD = oDtS + sDt;
    const size_t oWall = oDtD + sDt, oXs = oWall + sWall, oXd = oXs + sX;
    const size_t need  = oXd + sX;                        // ~149 MB

    if (ws_size >= need) {
        int* idx_s = (int*)((char*)d_ws + oIdxS);
        int* idx_d = (int*)((char*)d_ws + oIdxD);
        float* dt_s = (float*)((char*)d_ws + oDtS);
        float* dt_d = (float*)((char*)d_ws + oDtD);
        unsigned short* Wsw = (unsigned short*)((char*)d_ws + oWall);
        unsigned short* Xs  = (unsigned short*)((char*)d_ws + oXs);
        unsigned short* Xd  = (unsigned short*)((char*)d_ws + oXd);

        hipMemsetAsync(d_ws, 0xFF, 2 * sIdx, stream);     // idx arrays = -1
        scatter_last_kernel<<<(N_EDGES_C + 255) / 256, 256, 0, stream>>>(src, dst, idx_s, idx_d);
        build_wallsw_kernel<<<160, 256, 0, stream>>>(W_ih, W_hh, Wsw);
        gather_kernel<<<N_NODES_C / 16, 256, 0, stream>>>(
            memory, last_update, edge_times, edge_feat, src, dst,
            idx_s, idx_d, dt_s, dt_d, Xs, Xd, out_mem, out_lu);
        gemm_pass_kernel<0><<<GROUPS_PAD / 4, 256, 0, stream>>>(
            memory, Wsw, b_ih, b_hh, Xs, Xs, dt_s, idx_s, out_mem);
        gemm_pass_kernel<1><<<GROUPS_PAD / 4, 256, 0, stream>>>(
            memory, Wsw, b_ih, b_hh, Xd, Xs, dt_d, idx_d, out_mem);
    } else {
        // R2 fused fallback (needs ~1.5 MB ws)
        int* idx_s = (int*)d_ws;
        int* idx_d = idx_s + N_NODES_C;
        unsigned short* Wall = (unsigned short*)((char*)d_ws + 2 * N_NODES_C * sizeof(int));
        hipMemsetAsync(d_ws, 0xFF, 2 * N_NODES_C * sizeof(int), stream);
        scatter_last_kernel<<<(N_EDGES_C + 255) / 256, 256, 0, stream>>>(src, dst, idx_s, idx_d);
        build_wall_kernel<<<(WROWS * NXF + 255) / 256, 256, 0, stream>>>(W_ih, W_hh, Wall);
        gru_mfma_kernel<0><<<N_NODES_C / NODES_PB, 256, 0, stream>>>(
            memory, last_update, Wall, b_ih, b_hh, edge_times, edge_feat,
            src, dst, idx_s, out_mem, out_lu);
        gru_mfma_kernel<1><<<N_NODES_C / NODES_PB, 256, 0, stream>>>(
            memory, last_update, Wall, b_ih, b_hh, edge_times, edge_feat,
            src, dst, idx_d, out_mem, out_lu);
    }
}

// Round 6
// 474.840 us; speedup vs baseline: 1.3952x; 1.0221x over previous
//
#include <hip/hip_runtime.h>
#include <math.h>

// Problem constants (match reference file)
#define N_NODES_C 100000
#define DIM_C     128
#define DMSG_C    512
#define N_EDGES_C 200000

// GEMM geometry: 64 nodes/block (4 node-groups of 16), 512 gate rows = 32 tiles
#define GROUPS_PAD 6252            // 1563 blocks * 4 groups
#define NODES_PAD  (GROUPS_PAD*16) // 100032
#define XKK 12                     // X = [self|other|ef] = 384 cols = 12 kk-chunks of 32

typedef __attribute__((ext_vector_type(8))) __bf16 bf16x8;
typedef __attribute__((ext_vector_type(4))) float  f32x4;

__device__ __forceinline__ float sigmoidf_(float x) { return 1.0f / (1.0f + __expf(-x)); }
// fast tanh: 1 - 2/(e^{2x}+1); exact at +/-inf, ~1e-7 abs err mid-range (<< bf16 gemm noise)
__device__ __forceinline__ float tanhf_(float x) { return 1.0f - 2.0f / (__expf(2.0f * x) + 1.0f); }
__device__ __forceinline__ unsigned short f2bf(float x) {
    union { float f; unsigned u; } v; v.f = x;
    unsigned r = v.u + 0x7FFFu + ((v.u >> 16) & 1u);   // RNE
    return (unsigned short)(r >> 16);
}
__device__ __forceinline__ void st8(void* p, float4 lo, float4 hi) {
    union { bf16x8 v; unsigned short u[8]; } r;
    r.u[0] = f2bf(lo.x); r.u[1] = f2bf(lo.y); r.u[2] = f2bf(lo.z); r.u[3] = f2bf(lo.w);
    r.u[4] = f2bf(hi.x); r.u[5] = f2bf(hi.y); r.u[6] = f2bf(hi.z); r.u[7] = f2bf(hi.w);
    *(bf16x8*)p = r.v;
}

// ---- last occurrence of each node in edge order ----
__global__ void scatter_last_kernel(const int* __restrict__ src, const int* __restrict__ dst,
                                    int* __restrict__ idx_s, int* __restrict__ idx_d) {
    int e = blockIdx.x * blockDim.x + threadIdx.x;
    if (e < N_EDGES_C) {
        atomicMax(&idx_s[src[e]], e);
        atomicMax(&idx_d[dst[e]], e);
    }
}

// =====================  MAIN (split) PATH  =====================
// Wsw[tile][kk][lane][8]: B-fragment order. tile T: packed gate rows T*16+(l&15):
//   rows 0..127 r, 128..255 z, 256..383 i_n (W_ih), 384..511 h_n (W_hh rows 256..383)
// K map: 0..127 self, 128..255 other, 256..383 ef, 384..511 enc, 512..639 h
__global__ void build_wallsw_kernel(const float* __restrict__ W_ih, const float* __restrict__ W_hh,
                                    unsigned short* __restrict__ Wsw) {
    int id = blockIdx.x * 256 + threadIdx.x;           // 32*20*64 = 40960
    if (id >= 32 * 20 * 64) return;
    int tile = id / 1280, r = id - tile * 1280, kk = r >> 6, l = r & 63;
    int pr = tile * 16 + (l & 15);
    int k0 = kk * 32 + ((l >> 4) & 3) * 8;
    float v[8];
#pragma unroll
    for (int j = 0; j < 8; ++j) {
        int k = k0 + j;
        if (pr < 256)      v[j] = (k < 512) ? W_ih[(long)pr * DMSG_C + k] : W_hh[(long)pr * DIM_C + (k - 512)];
        else if (pr < 384) v[j] = (k < 512) ? W_ih[(long)pr * DMSG_C + k] : 0.0f;
        else               v[j] = (k >= 512) ? W_hh[(long)(pr - 128) * DIM_C + (k - 512)] : 0.0f;
    }
    union { bf16x8 bv; unsigned short u[8]; } o;
#pragma unroll
    for (int j = 0; j < 8; ++j) o.u[j] = f2bf(v[j]);
    *(bf16x8*)((char*)Wsw + ((size_t)(tile * 20 + kk) << 10) + ((size_t)l << 4)) = o.bv;
}

// Gather: 16 nodes/block. Builds Xs/Xd (A-frag-swizzled bf16), dt arrays, out_lu,
// and the inactive-pass0 copy of memory into out_mem.
__global__ __launch_bounds__(256) void gather_kernel(
    const float* __restrict__ memory, const float* __restrict__ last_update,
    const float* __restrict__ edge_times, const float* __restrict__ edge_feat,
    const int* __restrict__ src, const int* __restrict__ dst,
    const int* __restrict__ idx_s, const int* __restrict__ idx_d,
    float* __restrict__ dt_s, float* __restrict__ dt_d,
    unsigned short* __restrict__ Xs, unsigned short* __restrict__ Xd,
    float* __restrict__ out_mem, float* __restrict__ out_lu)
{
    __shared__ int es_l[16], ed_l[16], os_l[16], od_l[16];
    const int t = threadIdx.x;
    const int base = blockIdx.x * 16;
    if (t < 16) {
        const int n = base + t;
        const int es = idx_s[n], ed = idx_d[n];
        const int eus = es < 0 ? 0 : es, eud = ed < 0 ? 0 : ed;
        es_l[t] = es; ed_l[t] = ed;
        os_l[t] = dst[eus]; od_l[t] = src[eud];
        const float lun = last_update[n];
        const float ts = edge_times[eus], td = edge_times[eud];
        dt_s[n] = ts - lun; dt_d[n] = td - lun;
        out_lu[n] = (ed >= 0) ? td : ((es >= 0) ? ts : lun);
    }
    __syncthreads();
    const int m = t & 15, q = t >> 4;                  // node-in-block, col-chunk (8 cols)
    const int n = base + m;
    const size_t g = blockIdx.x;                       // node-group == block
    const int es = es_l[m];
    const int eus = (es < 0) ? 0 : es;
    const int eud = (ed_l[m] < 0) ? 0 : ed_l[m];
    const float4* self_p = (const float4*)(memory + (size_t)n * DIM_C + q * 8);
    const float4* oS_p   = (const float4*)(memory + (size_t)os_l[m] * DIM_C + q * 8);
    const float4* oD_p   = (const float4*)(memory + (size_t)od_l[m] * DIM_C + q * 8);
    const float4* eS_p   = (const float4*)(edge_feat + (size_t)eus * DIM_C + q * 8);
    const float4* eD_p   = (const float4*)(edge_feat + (size_t)eud * DIM_C + q * 8);
    float4 s0 = self_p[0], s1 = self_p[1];
    float4 a0 = oS_p[0],   a1 = oS_p[1];
    float4 b0 = oD_p[0],   b1 = oD_p[1];
    float4 c0 = eS_p[0],   c1 = eS_p[1];
    float4 d0 = eD_p[0],   d1 = eD_p[1];
    const int kkq = q >> 2;
    const size_t laneoff = (size_t)(((q & 3) * 16 + m)) << 4;
    char* XsB = (char*)Xs; char* XdB = (char*)Xd;
#define XOFF(kk) ((((g * XKK) + (kk)) << 10) + laneoff)
    st8(XsB + XOFF(kkq),     s0, s1);
    st8(XsB + XOFF(4 + kkq), a0, a1);
    st8(XsB + XOFF(8 + kkq), c0, c1);
    st8(XdB + XOFF(kkq),     s0, s1);
    st8(XdB + XOFF(4 + kkq), b0, b1);
    st8(XdB + XOFF(8 + kkq), d0, d1);
#undef XOFF
    if (es < 0) {   // inactive in pass0: seed out_mem with original memory row
        float4* op = (float4*)(out_mem + (size_t)n * DIM_C + q * 8);
        op[0] = s0; op[1] = s1;
    }
}

// GEMM+GRU pass, R8: counted-vmcnt pipeline with RAW barriers (no vmcnt(0)
// drain in the main loop — R7 post-mortem: __syncthreads' drain serialized
// every step behind full HBM latency; both MFMA and HBM floors are ~20 us
// but we ran at 129 us).
//
// 4 waves / 64 nodes; wave w owns gate-tiles {w,w+4,...,w+28}.
// LDS 64 KB: A 4-deep [slot4][nt4][1KB] @0; B 2-deep [buf2][wave4][s6][1KB] @16K.
// Per step, wave w issues exactly 7 DMA: [B(st+1) x6, A(st+2) x1], then
// s_waitcnt vmcnt(8) — in-order retirement retires exactly [A(st), B(st)x6]
// (invariant holds for all 20 steps incl. prologue; steps 18/19 issue dummy
// stages into provably-dead slots to preserve the count) — then a raw
// s_barrier publishes wave-w's A tile to the other waves. 2-step slack (~1k
// cyc) covers A's HBM latency; 1-step covers B's L2 latency.
// Step order: st 0..11 X (slots 0..5), st 12..15 H mirror (W kk 16..19,
// slots {0,1,2,3,6,7}), st 16..19 ENC in-register (W kk 12..15, slots 0..5).
__device__ __forceinline__ constexpr int kk_of_(int st) {
    return (st < 12) ? st : ((st < 16) ? st + 4 : st - 4);
}
__device__ __forceinline__ constexpr int slot_of_(int st, int s6) {
    return (st >= 12 && st < 16) ? ((s6 < 4) ? s6 : s6 + 2) : s6;
}

template <int PASS>
__global__ __launch_bounds__(256, 2) void gemm_pass_kernel(
    const float* __restrict__ memory,
    const unsigned short* __restrict__ Wsw,
    const float* __restrict__ b_ih, const float* __restrict__ b_hh,
    const unsigned short* __restrict__ Xsw,
    unsigned short* Hmir,                      // = Xs (self-block mirror; aliases Xsw in pass0)
    const float* __restrict__ dtp, const int* __restrict__ idxp,
    float* __restrict__ out_mem)
{
    __shared__ __align__(1024) char lds[65536];
    const int t = threadIdx.x;
    const int w = t >> 6, lane = t & 63, quad = lane >> 4, c = lane & 15;
    const long g0 = (long)blockIdx.x * 4;
    const char* Xb = (const char*)Xsw;
    const char* Hb = (const char*)Hmir;
    const char* Wb = (const char*)Wsw;
    const size_t laneoff = (size_t)lane << 4;

#define AOFF(slot, nt) (((slot) * 4 + (nt)) << 10)
#define BOFF(buf, s6)  (16384 + ((((buf) * 4 + w) * 6 + (s6)) << 10))

    // dt loads first; retire them BEFORE any staging so vmcnt counts stay exact
    float dtv[4];
#pragma unroll
    for (int nt = 0; nt < 4; ++nt) dtv[nt] = dtp[(g0 + nt) * 16 + c];
    asm volatile("s_waitcnt vmcnt(0)" ::: "memory");
    __builtin_amdgcn_sched_barrier(0);

    auto stage = [&](const char* gsrc, int ldsoff) {
        __builtin_amdgcn_global_load_lds(
            (const __attribute__((address_space(1))) void*)(gsrc + laneoff),
            (__attribute__((address_space(3))) void*)(lds + ldsoff), 16, 0, 0);
    };
    // A source for data-step k (k clamped to <=19 by callers; k>=16 is a dummy refetch)
    auto a_src = [&](int k) -> const char* {
        if (k < 12) return Xb + (((g0 + w) * XKK + k) << 10);
        if (k < 16) return Hb + (((g0 + w) * XKK + (k - 12)) << 10);
        return Hb + (((g0 + w) * XKK + 3) << 10);          // dummy (dead slot)
    };
    auto b_src = [&](int k, int s6) -> const char* {
        return Wb + ((size_t)((w + 4 * slot_of_(k, s6)) * 20 + kk_of_(k)) << 10);
    };

    f32x4 acc[8][4];
#pragma unroll
    for (int s = 0; s < 8; ++s)
#pragma unroll
        for (int nt = 0; nt < 4; ++nt) acc[s][nt] = (f32x4){0.f, 0.f, 0.f, 0.f};

    // ---- prologue: issue [B(0) x6, A(0), A(1)] (8 DMA) ----
#pragma unroll
    for (int s6 = 0; s6 < 6; ++s6) stage(b_src(0, s6), BOFF(0, s6));
    stage(a_src(0), AOFF(0, w));
    stage(a_src(1), AOFF(1, w));

#define MFMA_ROW(s, Bv) \
    acc[s][0] = __builtin_amdgcn_mfma_f32_16x16x32_bf16(A0, Bv, acc[s][0], 0, 0, 0); \
    acc[s][1] = __builtin_amdgcn_mfma_f32_16x16x32_bf16(A1, Bv, acc[s][1], 0, 0, 0); \
    acc[s][2] = __builtin_amdgcn_mfma_f32_16x16x32_bf16(A2, Bv, acc[s][2], 0, 0, 0); \
    acc[s][3] = __builtin_amdgcn_mfma_f32_16x16x32_bf16(A3, Bv, acc[s][3], 0, 0, 0)

#pragma unroll
    for (int st = 0; st < 20; ++st) {
        // issue G_st = [B(st+1) x6, A(st+2)] (dummies past the end keep the count)
        const int kb = (st + 1 <= 19) ? st + 1 : 19;
#pragma unroll
        for (int s6 = 0; s6 < 6; ++s6) stage(b_src(kb, s6), BOFF((st + 1) & 1, s6));
        const int ka = (st + 2 <= 19) ? st + 2 : 19;
        stage(a_src(ka), AOFF((st + 2) & 3, w));

        // counted wait: retires exactly [A(st), B(st) x6]; 8 stay in flight
        asm volatile("s_waitcnt vmcnt(8)" ::: "memory");
        __builtin_amdgcn_sched_barrier(0);
        __builtin_amdgcn_s_barrier();          // raw: publish A(st), NO drain
        __builtin_amdgcn_sched_barrier(0);

        bf16x8 A0, A1, A2, A3;
        if (st < 16) {
            A0 = *(const bf16x8*)(lds + AOFF(st & 3, 0) + laneoff);
            A1 = *(const bf16x8*)(lds + AOFF(st & 3, 1) + laneoff);
            A2 = *(const bf16x8*)(lds + AOFF(st & 3, 2) + laneoff);
            A3 = *(const bf16x8*)(lds + AOFF(st & 3, 3) + laneoff);
        } else {
            // ENC: A = cos(dt * w_f) computed in-register
            const int ec = st - 16;
            const int f0 = ec * 32 + quad * 8;
            float wf[8];
#pragma unroll
            for (int j = 0; j < 8; ++j) wf[j] = __expf(-0.16317532f * (float)(f0 + j));
            union { bf16x8 v; unsigned short u[8]; } r0, r1, r2, r3;
#pragma unroll
            for (int j = 0; j < 8; ++j) {
                r0.u[j] = f2bf(__cosf(dtv[0] * wf[j]));
                r1.u[j] = f2bf(__cosf(dtv[1] * wf[j]));
                r2.u[j] = f2bf(__cosf(dtv[2] * wf[j]));
                r3.u[j] = f2bf(__cosf(dtv[3] * wf[j]));
            }
            A0 = r0.v; A1 = r1.v; A2 = r2.v; A3 = r3.v;
        }
        bf16x8 B0 = *(const bf16x8*)(lds + BOFF(st & 1, 0) + laneoff);
        bf16x8 B1 = *(const bf16x8*)(lds + BOFF(st & 1, 1) + laneoff);
        bf16x8 B2 = *(const bf16x8*)(lds + BOFF(st & 1, 2) + laneoff);
        bf16x8 B3 = *(const bf16x8*)(lds + BOFF(st & 1, 3) + laneoff);
        bf16x8 B4 = *(const bf16x8*)(lds + BOFF(st & 1, 4) + laneoff);
        bf16x8 B5 = *(const bf16x8*)(lds + BOFF(st & 1, 5) + laneoff);

        __builtin_amdgcn_s_setprio(1);
        if (st >= 12 && st < 16) {
            MFMA_ROW(0, B0); MFMA_ROW(1, B1); MFMA_ROW(2, B2);
            MFMA_ROW(3, B3); MFMA_ROW(6, B4); MFMA_ROW(7, B5);
        } else {
            MFMA_ROW(0, B0); MFMA_ROW(1, B1); MFMA_ROW(2, B2);
            MFMA_ROW(3, B3); MFMA_ROW(4, B4); MFMA_ROW(5, B5);
        }
        __builtin_amdgcn_s_setprio(0);
    }
#undef MFMA_ROW
#undef AOFF
#undef BOFF

    // ---- Epilogue (batched loads): lane owns node (g0+nt)*16 + quad*4 + reg,
    //      dims j = (w+4p)*16 + c ----
    const float* hsrc = (PASS == 0) ? memory : out_mem;

    int ebuf[4][4];
#pragma unroll
    for (int nt = 0; nt < 4; ++nt)
#pragma unroll
        for (int reg = 0; reg < 4; ++reg) {
            const long n = (g0 + nt) * 16 + quad * 4 + reg;
            ebuf[nt][reg] = (n < N_NODES_C) ? idxp[n] : -1;
        }

    float hbuf[2][4][4];
#pragma unroll
    for (int p = 0; p < 2; ++p) {
        const int j = (w + 4 * p) * 16 + c;
#pragma unroll
        for (int nt = 0; nt < 4; ++nt)
#pragma unroll
            for (int reg = 0; reg < 4; ++reg) {
                const long n = (g0 + nt) * 16 + quad * 4 + reg;
                hbuf[p][nt][reg] = hsrc[(size_t)(n < N_NODES_C ? n : 0) * DIM_C + j];
            }
    }

#pragma unroll
    for (int p = 0; p < 2; ++p) {
        const int j = (w + 4 * p) * 16 + c;
        const float br = b_ih[j] + b_hh[j];
        const float bz = b_ih[128 + j] + b_hh[128 + j];
        const float bi = b_ih[256 + j];
        const float bh = b_hh[256 + j];
        // bf16-mirror address components for dim j (A-frag layout within self block)
        const int kkm = j >> 5;
        const int q2  = (j >> 3) & 3;
        const int bb  = j & 7;
#pragma unroll
        for (int nt = 0; nt < 4; ++nt) {
#pragma unroll
            for (int reg = 0; reg < 4; ++reg) {
                const long n = (g0 + nt) * 16 + quad * 4 + reg;
                if (n < N_NODES_C && ebuf[nt][reg] >= 0) {
                    const float r  = sigmoidf_(acc[0 + p][nt][reg] + br);
                    const float z  = sigmoidf_(acc[2 + p][nt][reg] + bz);
                    const float nn = tanhf_(acc[4 + p][nt][reg] + bi + r * (acc[6 + p][nt][reg] + bh));
                    const float h  = hbuf[p][nt][reg];
                    const float hnew = (1.0f - z) * nn + z * h;
                    out_mem[(size_t)n * DIM_C + j] = hnew;
                    if (PASS == 0) {
                        const int row = quad * 4 + reg;
                        *(unsigned short*)((char*)Hmir + (((g0 + nt) * XKK + kkm) << 10)
                                           + ((q2 * 16 + row) << 4) + (bb << 1)) = f2bf(hnew);
                    }
                }
            }
        }
    }
}

// =====================  FALLBACK (R2 fused) PATH  =====================
#define NODES_PB  32
#define LDSW      648
#define WROWS     512
#define NXF       640

__global__ void build_wall_kernel(const float* __restrict__ W_ih, const float* __restrict__ W_hh,
                                  unsigned short* __restrict__ Wall) {
    int i = blockIdx.x * 256 + threadIdx.x;
    if (i >= WROWS * NXF) return;
    int r = i / NXF, k = i - r * NXF;
    float v;
    if (r < 256)      v = (k < 512) ? W_ih[(long)r * DMSG_C + k] : W_hh[(long)r * DIM_C + (k - 512)];
    else if (r < 384) v = (k < 512) ? W_ih[(long)r * DMSG_C + k] : 0.0f;
    else              v = (k >= 512) ? W_hh[(long)(r - 128) * DIM_C + (k - 512)] : 0.0f;
    Wall[i] = f2bf(v);
}

template <int PASS>
__global__ __launch_bounds__(256) void gru_mfma_kernel(
    const float* __restrict__ memory, const float* __restrict__ last_update,
    const unsigned short* __restrict__ Wall,
    const float* __restrict__ b_ih, const float* __restrict__ b_hh,
    const float* __restrict__ edge_times, const float* __restrict__ edge_feat,
    const int* __restrict__ src, const int* __restrict__ dst,
    const int* __restrict__ idx,
    float* __restrict__ out_mem, float* __restrict__ out_lu)
{
    __shared__ __align__(16) unsigned short Xl[NODES_PB][LDSW];
    __shared__ int eidx[NODES_PB];
    const int t = threadIdx.x;
    const int base = blockIdx.x * NODES_PB;
    if (t < NODES_PB) eidx[t] = idx[base + t];
    __syncthreads();
    const int tt = t & 127;
    const int sh = t >> 7;
    const float wfreq = __expf(-0.16317532f * (float)tt);
    for (int s0 = 0; s0 < NODES_PB; s0 += 2) {
        const int s = s0 + sh;
        const int n = base + s;
        const int e = eidx[s];
        const int eu = (e >= 0) ? e : 0;
        const int other = (PASS == 0) ? dst[eu] : src[eu];
        const float mself = memory[(long)n * DIM_C + tt];
        const float moth  = memory[(long)other * DIM_C + tt];
        const float ef    = edge_feat[(long)eu * DIM_C + tt];
        const float dt    = edge_times[eu] - last_update[n];
        const float enc   = __cosf(dt * wfreq);
        const float hv    = (PASS == 0) ? mself : out_mem[(long)n * DIM_C + tt];
        Xl[s][tt]       = f2bf(mself);
        Xl[s][128 + tt] = f2bf(moth);
        Xl[s][256 + tt] = f2bf(ef);
        Xl[s][384 + tt] = f2bf(enc);
        Xl[s][512 + tt] = f2bf(hv);
    }
    __syncthreads();
    const int w = t >> 6, lane = t & 63;
    const int quad = lane >> 4, c = lane & 15;
    f32x4 acc[8][2];
#pragma unroll
    for (int i = 0; i < 8; ++i)
#pragma unroll
        for (int mt = 0; mt < 2; ++mt) acc[i][mt] = (f32x4){0.f, 0.f, 0.f, 0.f};
    const unsigned short* wrow[8];
#pragma unroll
    for (int i = 0; i < 8; ++i)
        wrow[i] = Wall + (long)((w + 4 * i) * 16 + c) * NXF + quad * 8;
    for (int kk = 0; kk < 16; ++kk) {
        const int k0 = kk * 32;
        bf16x8 a0 = *(const bf16x8*)&Xl[c][k0 + quad * 8];
        bf16x8 a1 = *(const bf16x8*)&Xl[16 + c][k0 + quad * 8];
#pragma unroll
        for (int i = 0; i < 6; ++i) {
            bf16x8 b = *(const bf16x8*)(wrow[i] + k0);
            acc[i][0] = __builtin_amdgcn_mfma_f32_16x16x32_bf16(a0, b, acc[i][0], 0, 0, 0);
            acc[i][1] = __builtin_amdgcn_mfma_f32_16x16x32_bf16(a1, b, acc[i][1], 0, 0, 0);
        }
    }
    for (int kk = 16; kk < 20; ++kk) {
        const int k0 = kk * 32;
        bf16x8 a0 = *(const bf16x8*)&Xl[c][k0 + quad * 8];
        bf16x8 a1 = *(const bf16x8*)&Xl[16 + c][k0 + quad * 8];
#pragma unroll
        for (int ii = 0; ii < 6; ++ii) {
            const int i = (ii < 4) ? ii : ii + 2;
            bf16x8 b = *(const bf16x8*)(wrow[i] + k0);
            acc[i][0] = __builtin_amdgcn_mfma_f32_16x16x32_bf16(a0, b, acc[i][0], 0, 0, 0);
            acc[i][1] = __builtin_amdgcn_mfma_f32_16x16x32_bf16(a1, b, acc[i][1], 0, 0, 0);
        }
    }
    const float* hsrc = (PASS == 0) ? memory : out_mem;
#pragma unroll
    for (int p = 0; p < 2; ++p) {
        const int j = (w + 4 * p) * 16 + c;
        const float br = b_ih[j] + b_hh[j];
        const float bz = b_ih[128 + j] + b_hh[128 + j];
        const float bi = b_ih[256 + j];
        const float bh = b_hh[256 + j];
#pragma unroll
        for (int mt = 0; mt < 2; ++mt) {
#pragma unroll
            for (int reg = 0; reg < 4; ++reg) {
                const int ml = mt * 16 + quad * 4 + reg;
                const int n = base + ml;
                const int e = eidx[ml];
                const float h = hsrc[(long)n * DIM_C + j];
                if (e >= 0) {
                    const float r  = sigmoidf_(acc[p][mt][reg] + br);
                    const float z  = sigmoidf_(acc[p + 2][mt][reg] + bz);
                    const float nn = tanhf_(acc[p + 4][mt][reg] + bi + r * (acc[p + 6][mt][reg] + bh));
                    out_mem[(long)n * DIM_C + j] = (1.0f - z) * nn + z * h;
                } else if (PASS == 0) {
                    out_mem[(long)n * DIM_C + j] = h;
                }
            }
        }
    }
    if (t < NODES_PB) {
        const int n = base + t;
        const int e = eidx[t];
        if (e >= 0)         out_lu[n] = edge_times[e];
        else if (PASS == 0) out_lu[n] = last_update[n];
    }
}

// =====================  LAUNCH  =====================
extern "C" void kernel_launch(void* const* d_in, const int* in_sizes, int n_in,
                              void* d_out, int out_size, void* d_ws, size_t ws_size,
                              hipStream_t stream) {
    const float* memory      = (const float*)d_in[0];
    const float* last_update = (const float*)d_in[1];
    const float* W_ih        = (const float*)d_in[2];
    const float* W_hh        = (const float*)d_in[3];
    const float* b_ih        = (const float*)d_in[4];
    const float* b_hh        = (const float*)d_in[5];
    const float* edge_times  = (const float*)d_in[6];
    const float* edge_feat   = (const float*)d_in[7];
    const int*   src         = (const int*)d_in[8];
    const int*   dst         = (const int*)d_in[9];

    float* out_mem = (float*)d_out;
    float* out_lu  = out_mem + (size_t)N_NODES_C * DIM_C;

    // ws layout (main path)
    const size_t sIdx  = (size_t)NODES_PAD * 4;           // 400128 B each
    const size_t sDt   = (size_t)NODES_PAD * 4;
    const size_t sWall = (size_t)32 * 20 * 1024;          // 655360 B
    const size_t sX    = (size_t)GROUPS_PAD * XKK * 1024; // 76.8 MB each
    const size_t oIdxS = 0, oIdxD = oIdxS + sIdx, oDtS = oIdxD + sIdx, oDtD = oDtS + sDt;
    const size_t oWall = oDtD + sDt, oXs = oWall + sWall, oXd = oXs + sX;
    const size_t need  = oXd + sX;                        // ~149 MB

    if (ws_size >= need) {
        int* idx_s = (int*)((char*)d_ws + oIdxS);
        int* idx_d = (int*)((char*)d_ws + oIdxD);
        float* dt_s = (float*)((char*)d_ws + oDtS);
        float* dt_d = (float*)((char*)d_ws + oDtD);
        unsigned short* Wsw = (unsigned short*)((char*)d_ws + oWall);
        unsigned short* Xs  = (unsigned short*)((char*)d_ws + oXs);
        unsigned short* Xd  = (unsigned short*)((char*)d_ws + oXd);

        hipMemsetAsync(d_ws, 0xFF, 2 * sIdx, stream);     // idx arrays = -1
        scatter_last_kernel<<<(N_EDGES_C + 255) / 256, 256, 0, stream>>>(src, dst, idx_s, idx_d);
        build_wallsw_kernel<<<160, 256, 0, stream>>>(W_ih, W_hh, Wsw);
        gather_kernel<<<N_NODES_C / 16, 256, 0, stream>>>(
            memory, last_update, edge_times, edge_feat, src, dst,
            idx_s, idx_d, dt_s, dt_d, Xs, Xd, out_mem, out_lu);
        gemm_pass_kernel<0><<<GROUPS_PAD / 4, 256, 0, stream>>>(
            memory, Wsw, b_ih, b_hh, Xs, Xs, dt_s, idx_s, out_mem);
        gemm_pass_kernel<1><<<GROUPS_PAD / 4, 256, 0, stream>>>(
            memory, Wsw, b_ih, b_hh, Xd, Xs, dt_d, idx_d, out_mem);
    } else {
        // R2 fused fallback (needs ~1.5 MB ws)
        int* idx_s = (int*)d_ws;
        int* idx_d = idx_s + N_NODES_C;
        unsigned short* Wall = (unsigned short*)((char*)d_ws + 2 * N_NODES_C * sizeof(int));
        hipMemsetAsync(d_ws, 0xFF, 2 * N_NODES_C * sizeof(int), stream);
        scatter_last_kernel<<<(N_EDGES_C + 255) / 256, 256, 0, stream>>>(src, dst, idx_s, idx_d);
        build_wall_kernel<<<(WROWS * NXF + 255) / 256, 256, 0, stream>>>(W_ih, W_hh, Wall);
        gru_mfma_kernel<0><<<N_NODES_C / NODES_PB, 256, 0, stream>>>(
            memory, last_update, Wall, b_ih, b_hh, edge_times, edge_feat,
            src, dst, idx_s, out_mem, out_lu);
        gru_mfma_kernel<1><<<N_NODES_C / NODES_PB, 256, 0, stream>>>(
            memory, last_update, Wall, b_ih, b_hh, edge_times, edge_feat,
            src, dst, idx_d, out_mem, out_lu);
    }
}

// Round 7
// 468.484 us; speedup vs baseline: 1.4142x; 1.0136x over previous
//
#include <hip/hip_runtime.h>
#include <math.h>

// Problem constants (match reference file)
#define N_NODES_C 100000
#define DIM_C     128
#define DMSG_C    512
#define N_EDGES_C 200000

// GEMM geometry: 128 nodes/block (8 node-groups of 16), 512 gate rows = 32 tiles
#define GROUPS_PAD 6256            // 782 gemm blocks * 8 groups
#define NODES_PAD  (GROUPS_PAD*16) // 100096
#define XKK 12                     // X = [self|other|ef] = 384 cols = 12 kk-chunks of 32

typedef __attribute__((ext_vector_type(8))) __bf16 bf16x8;
typedef __attribute__((ext_vector_type(4))) float  f32x4;

__device__ __forceinline__ float sigmoidf_(float x) { return 1.0f / (1.0f + __expf(-x)); }
// fast tanh: 1 - 2/(e^{2x}+1); exact at +/-inf, ~1e-7 abs err mid-range (<< bf16 gemm noise)
__device__ __forceinline__ float tanhf_(float x) { return 1.0f - 2.0f / (__expf(2.0f * x) + 1.0f); }
__device__ __forceinline__ unsigned short f2bf(float x) {
    union { float f; unsigned u; } v; v.f = x;
    unsigned r = v.u + 0x7FFFu + ((v.u >> 16) & 1u);   // RNE
    return (unsigned short)(r >> 16);
}
__device__ __forceinline__ void st8(void* p, float4 lo, float4 hi) {
    union { bf16x8 v; unsigned short u[8]; } r;
    r.u[0] = f2bf(lo.x); r.u[1] = f2bf(lo.y); r.u[2] = f2bf(lo.z); r.u[3] = f2bf(lo.w);
    r.u[4] = f2bf(hi.x); r.u[5] = f2bf(hi.y); r.u[6] = f2bf(hi.z); r.u[7] = f2bf(hi.w);
    *(bf16x8*)p = r.v;
}

// ---- last occurrence of each node in edge order ----
__global__ void scatter_last_kernel(const int* __restrict__ src, const int* __restrict__ dst,
                                    int* __restrict__ idx_s, int* __restrict__ idx_d) {
    int e = blockIdx.x * blockDim.x + threadIdx.x;
    if (e < N_EDGES_C) {
        atomicMax(&idx_s[src[e]], e);
        atomicMax(&idx_d[dst[e]], e);
    }
}

// =====================  MAIN (split) PATH  =====================
// Wsw[tile][kk][lane][8]: B-fragment order. tile T: packed gate rows T*16+(l&15):
//   tiles 0-7 r, 8-15 z, 16-23 i_n (W_ih), 24-31 h_n (W_hh rows 256..383)
// K map: 0..127 self, 128..255 other, 256..383 ef, 384..511 enc, 512..639 h
__global__ void build_wallsw_kernel(const float* __restrict__ W_ih, const float* __restrict__ W_hh,
                                    unsigned short* __restrict__ Wsw) {
    int id = blockIdx.x * 256 + threadIdx.x;           // 32*20*64 = 40960
    if (id >= 32 * 20 * 64) return;
    int tile = id / 1280, r = id - tile * 1280, kk = r >> 6, l = r & 63;
    int pr = tile * 16 + (l & 15);
    int k0 = kk * 32 + ((l >> 4) & 3) * 8;
    float v[8];
#pragma unroll
    for (int j = 0; j < 8; ++j) {
        int k = k0 + j;
        if (pr < 256)      v[j] = (k < 512) ? W_ih[(long)pr * DMSG_C + k] : W_hh[(long)pr * DIM_C + (k - 512)];
        else if (pr < 384) v[j] = (k < 512) ? W_ih[(long)pr * DMSG_C + k] : 0.0f;
        else               v[j] = (k >= 512) ? W_hh[(long)(pr - 128) * DIM_C + (k - 512)] : 0.0f;
    }
    union { bf16x8 bv; unsigned short u[8]; } o;
#pragma unroll
    for (int j = 0; j < 8; ++j) o.u[j] = f2bf(v[j]);
    *(bf16x8*)((char*)Wsw + ((size_t)(tile * 20 + kk) << 10) + ((size_t)l << 4)) = o.bv;
}

// Gather: 16 nodes/block. Builds Xs/Xd (A-frag-swizzled bf16), dt arrays, out_lu,
// and the inactive-pass0 copy of memory into out_mem. Grid covers real nodes only;
// padded groups stay garbage (their gemm outputs are masked by idx=-1).
__global__ __launch_bounds__(256) void gather_kernel(
    const float* __restrict__ memory, const float* __restrict__ last_update,
    const float* __restrict__ edge_times, const float* __restrict__ edge_feat,
    const int* __restrict__ src, const int* __restrict__ dst,
    const int* __restrict__ idx_s, const int* __restrict__ idx_d,
    float* __restrict__ dt_s, float* __restrict__ dt_d,
    unsigned short* __restrict__ Xs, unsigned short* __restrict__ Xd,
    float* __restrict__ out_mem, float* __restrict__ out_lu)
{
    __shared__ int es_l[16], ed_l[16], os_l[16], od_l[16];
    const int t = threadIdx.x;
    const int base = blockIdx.x * 16;
    if (t < 16) {
        const int n = base + t;
        const int es = idx_s[n], ed = idx_d[n];
        const int eus = es < 0 ? 0 : es, eud = ed < 0 ? 0 : ed;
        es_l[t] = es; ed_l[t] = ed;
        os_l[t] = dst[eus]; od_l[t] = src[eud];
        const float lun = last_update[n];
        const float ts = edge_times[eus], td = edge_times[eud];
        dt_s[n] = ts - lun; dt_d[n] = td - lun;
        out_lu[n] = (ed >= 0) ? td : ((es >= 0) ? ts : lun);
    }
    __syncthreads();
    const int m = t & 15, q = t >> 4;                  // node-in-block, col-chunk (8 cols)
    const int n = base + m;
    const size_t g = blockIdx.x;                       // node-group == block
    const int es = es_l[m];
    const int eus = (es < 0) ? 0 : es;
    const int eud = (ed_l[m] < 0) ? 0 : ed_l[m];
    const float4* self_p = (const float4*)(memory + (size_t)n * DIM_C + q * 8);
    const float4* oS_p   = (const float4*)(memory + (size_t)os_l[m] * DIM_C + q * 8);
    const float4* oD_p   = (const float4*)(memory + (size_t)od_l[m] * DIM_C + q * 8);
    const float4* eS_p   = (const float4*)(edge_feat + (size_t)eus * DIM_C + q * 8);
    const float4* eD_p   = (const float4*)(edge_feat + (size_t)eud * DIM_C + q * 8);
    float4 s0 = self_p[0], s1 = self_p[1];
    float4 a0 = oS_p[0],   a1 = oS_p[1];
    float4 b0 = oD_p[0],   b1 = oD_p[1];
    float4 c0 = eS_p[0],   c1 = eS_p[1];
    float4 d0 = eD_p[0],   d1 = eD_p[1];
    const int kkq = q >> 2;
    const size_t laneoff = (size_t)(((q & 3) * 16 + m)) << 4;
    char* XsB = (char*)Xs; char* XdB = (char*)Xd;
#define XOFF(kk) ((((g * XKK) + (kk)) << 10) + laneoff)
    st8(XsB + XOFF(kkq),     s0, s1);
    st8(XsB + XOFF(4 + kkq), a0, a1);
    st8(XsB + XOFF(8 + kkq), c0, c1);
    st8(XdB + XOFF(kkq),     s0, s1);
    st8(XdB + XOFF(4 + kkq), b0, b1);
    st8(XdB + XOFF(8 + kkq), d0, d1);
#undef XOFF
    if (es < 0) {   // inactive in pass0: seed out_mem with original memory row
        float4* op = (float4*)(out_mem + (size_t)n * DIM_C + q * 8);
        op[0] = s0; op[1] = s1;
    }
}

// GEMM+GRU pass, R9: 512 threads = 8 waves over 128 nodes (8 groups).
// Wave w owns gate tiles {w, w+8, w+16, w+24} = one r/z/i/hn tile, all at
// output dims j = w*16+c; acc[4 gate][8 group]. B tiles are now WAVE-PRIVATE
// 3-per-step (r,z,i or r,z,hn) -> per-CU DMA drops 56->32 KB/step vs R8 and
// chip-wide B refetch halves (R8 post-mortem: per-CU VMEM line-rate is the
// suspected binding resource; both co-resident R8 blocks fetched the same B).
//
// LDS 112 KB: A 4-deep [slot4][g8][1KB] @0; B 2-deep [buf2][w8][si3][1KB] @32K;
// ENC [ec4][g8][1KB] @80K (computed once in prologue DMA shadow).
// Counted vmcnt (static schedule), raw s_barrier only while A-steps remain
// (st<=15); steps 16..19 (ENC) run barrier-free, B wave-private.
// Step order: st 0..11 X (W kk st, gates r,z,i), st 12..15 H mirror (W kk
// st+4, gates r,z,hn), st 16..19 ENC from LDS (W kk st-4, gates r,z,i).
template <int PASS>
__global__ __launch_bounds__(512, 2) void gemm_pass_kernel(
    const float* __restrict__ memory,
    const unsigned short* __restrict__ Wsw,
    const float* __restrict__ b_ih, const float* __restrict__ b_hh,
    const unsigned short* __restrict__ Xsw,
    unsigned short* Hmir,                      // = Xs (self-block mirror; aliases Xsw in pass0)
    const float* __restrict__ dtp, const int* __restrict__ idxp,
    float* __restrict__ out_mem)
{
    __shared__ __align__(1024) char lds[114688];
    const int t = threadIdx.x;
    const int w = t >> 6, lane = t & 63, quad = lane >> 4, c = lane & 15;
    const long g0 = (long)blockIdx.x * 8;
    const char* Xb = (const char*)Xsw;
    const char* Hb = (const char*)Hmir;
    const char* Wb = (const char*)Wsw;
    const size_t laneoff = (size_t)lane << 4;

#define AOFF(slot, g) ((((slot) * 8) + (g)) << 10)                    // 32 KB
#define BOFF(buf, si) (32768 + ((((buf) * 8 + w) * 3 + (si)) << 10))  // 48 KB
#define EOFF(ec, g)   (81920 + ((((ec) * 8) + (g)) << 10))            // 32 KB

    // ---- dt loads for this wave's ENC half (retire before staging: exact vmcnt) ----
    const int ecw = w & 3, gh = (w >> 2) * 4;
    float dtv[4];
#pragma unroll
    for (int g2 = 0; g2 < 4; ++g2) dtv[g2] = dtp[(g0 + gh + g2) * 16 + c];
    asm volatile("s_waitcnt vmcnt(0)" ::: "memory");
    __builtin_amdgcn_sched_barrier(0);

    auto stage = [&](const char* gsrc, int ldsoff) {
        __builtin_amdgcn_global_load_lds(
            (const __attribute__((address_space(1))) void*)(gsrc + laneoff),
            (__attribute__((address_space(3))) void*)(lds + ldsoff), 16, 0, 0);
    };
    // A source for data-step k (k in 0..15)
    auto a_src = [&](int k) -> const char* {
        return (k < 12) ? (Xb + (((g0 + w) * XKK + k) << 10))
                        : (Hb + (((g0 + w) * XKK + (k - 12)) << 10));
    };
    // B tile for step k, slot-index si (0:r, 1:z, 2: i or hn)
    auto b_src = [&](int k, int si) -> const char* {
        const bool hph = (k >= 12 && k < 16);
        const int tile = (si < 2) ? (w + 8 * si) : (hph ? (w + 24) : (w + 16));
        const int kk = (k < 12) ? k : (hph ? k + 4 : k - 4);
        return Wb + ((size_t)(tile * 20 + kk) << 10);
    };

    f32x4 acc[4][8];
#pragma unroll
    for (int s = 0; s < 4; ++s)
#pragma unroll
        for (int g = 0; g < 8; ++g) acc[s][g] = (f32x4){0.f, 0.f, 0.f, 0.f};

    // ---- prologue: issue [B(0)x3, A(0), A(1)] then compute ENC (DMA shadow) ----
#pragma unroll
    for (int si = 0; si < 3; ++si) stage(b_src(0, si), BOFF(0, si));
    stage(a_src(0), AOFF(0, w));
    stage(a_src(1), AOFF(1, w));

    {   // ENC fragments: wave w fills chunk (w&3), groups gh..gh+3.
        const int f0 = ecw * 32 + quad * 8;
        float wf[8];
#pragma unroll
        for (int j = 0; j < 8; ++j) wf[j] = __expf(-0.16317532f * (float)(f0 + j));
#pragma unroll
        for (int g2 = 0; g2 < 4; ++g2) {
            union { bf16x8 v; unsigned short u[8]; } r;
#pragma unroll
            for (int j = 0; j < 8; ++j) r.u[j] = f2bf(__cosf(dtv[g2] * wf[j]));
            *(bf16x8*)(lds + EOFF(ecw, gh + g2) + laneoff) = r.v;
        }
    }
    asm volatile("s_waitcnt lgkmcnt(0)" ::: "memory");   // ENC ds_writes done
    __builtin_amdgcn_sched_barrier(0);
    __builtin_amdgcn_s_barrier();                        // publish ENC (no vm drain)
    __builtin_amdgcn_sched_barrier(0);

#define MFMA_G(s, Bv, Av, g) \
    acc[s][g] = __builtin_amdgcn_mfma_f32_16x16x32_bf16(Av, Bv, acc[s][g], 0, 0, 0)
#define MFMA_ROW(s, Bv) \
    MFMA_G(s, Bv, A[0], 0); MFMA_G(s, Bv, A[1], 1); MFMA_G(s, Bv, A[2], 2); \
    MFMA_G(s, Bv, A[3], 3); MFMA_G(s, Bv, A[4], 4); MFMA_G(s, Bv, A[5], 5); \
    MFMA_G(s, Bv, A[6], 6); MFMA_G(s, Bv, A[7], 7)

#pragma unroll
    for (int st = 0; st < 20; ++st) {
        // stage next: B(st+1) x3 (if any), A(st+2) (if <=15)
        if (st + 1 <= 19) {
#pragma unroll
            for (int si = 0; si < 3; ++si)
                stage(b_src(st + 1, si), BOFF((st + 1) & 1, si));
        }
        if (st + 2 <= 15) stage(a_src(st + 2), AOFF((st + 2) & 3, w));

        // static counted wait (in-order retirement; per-wave exact)
        if (st <= 13)      asm volatile("s_waitcnt vmcnt(5)" ::: "memory");
        else if (st == 14) asm volatile("s_waitcnt vmcnt(4)" ::: "memory");
        else if (st <= 18) asm volatile("s_waitcnt vmcnt(3)" ::: "memory");
        else               asm volatile("s_waitcnt vmcnt(0)" ::: "memory");
        __builtin_amdgcn_sched_barrier(0);
        if (st <= 15) {                       // publish A(st); ENC steps barrier-free
            __builtin_amdgcn_s_barrier();
            __builtin_amdgcn_sched_barrier(0);
        }

        bf16x8 A[8];
        if (st < 16) {
#pragma unroll
            for (int g = 0; g < 8; ++g)
                A[g] = *(const bf16x8*)(lds + AOFF(st & 3, g) + laneoff);
        } else {
#pragma unroll
            for (int g = 0; g < 8; ++g)
                A[g] = *(const bf16x8*)(lds + EOFF(st - 16, g) + laneoff);
        }
        bf16x8 B0 = *(const bf16x8*)(lds + BOFF(st & 1, 0) + laneoff);
        bf16x8 B1 = *(const bf16x8*)(lds + BOFF(st & 1, 1) + laneoff);
        bf16x8 B2 = *(const bf16x8*)(lds + BOFF(st & 1, 2) + laneoff);

        const bool hph = (st >= 12 && st < 16);
        __builtin_amdgcn_s_setprio(1);
        MFMA_ROW(0, B0);
        MFMA_ROW(1, B1);
        if (hph) { MFMA_ROW(3, B2); } else { MFMA_ROW(2, B2); }
        __builtin_amdgcn_s_setprio(0);
    }
#undef MFMA_ROW
#undef MFMA_G
#undef AOFF
#undef BOFF
#undef EOFF

    // ---- Epilogue: lane owns dim j = w*16+c for nodes (g0+g)*16 + quad*4 + reg ----
    const float* hsrc = (PASS == 0) ? memory : out_mem;
    const int j = w * 16 + c;
    const float br = b_ih[j] + b_hh[j];
    const float bz = b_ih[128 + j] + b_hh[128 + j];
    const float bi = b_ih[256 + j];
    const float bh = b_hh[256 + j];
    const int kkm = j >> 5, q2 = (j >> 3) & 3, bb = j & 7;

    int ebuf[8][4];
#pragma unroll
    for (int g = 0; g < 8; ++g)
#pragma unroll
        for (int reg = 0; reg < 4; ++reg) {
            const long n = (g0 + g) * 16 + quad * 4 + reg;
            ebuf[g][reg] = (n < N_NODES_C) ? idxp[n] : -1;
        }
    float hbuf[8][4];
#pragma unroll
    for (int g = 0; g < 8; ++g)
#pragma unroll
        for (int reg = 0; reg < 4; ++reg) {
            const long n = (g0 + g) * 16 + quad * 4 + reg;
            hbuf[g][reg] = hsrc[(size_t)(n < N_NODES_C ? n : 0) * DIM_C + j];
        }

#pragma unroll
    for (int g = 0; g < 8; ++g) {
#pragma unroll
        for (int reg = 0; reg < 4; ++reg) {
            const long n = (g0 + g) * 16 + quad * 4 + reg;
            if (n < N_NODES_C && ebuf[g][reg] >= 0) {
                const float r  = sigmoidf_(acc[0][g][reg] + br);
                const float z  = sigmoidf_(acc[1][g][reg] + bz);
                const float nn = tanhf_(acc[2][g][reg] + bi + r * (acc[3][g][reg] + bh));
                const float h  = hbuf[g][reg];
                const float hnew = (1.0f - z) * nn + z * h;
                out_mem[(size_t)n * DIM_C + j] = hnew;
                if (PASS == 0) {
                    const int row = quad * 4 + reg;
                    *(unsigned short*)((char*)Hmir + (((g0 + g) * XKK + kkm) << 10)
                                       + ((q2 * 16 + row) << 4) + (bb << 1)) = f2bf(hnew);
                }
            }
        }
    }
}

// =====================  FALLBACK (R2 fused) PATH  =====================
#define NODES_PB  32
#define LDSW      648
#define WROWS     512
#define NXF       640

__global__ void build_wall_kernel(const float* __restrict__ W_ih, const float* __restrict__ W_hh,
                                  unsigned short* __restrict__ Wall) {
    int i = blockIdx.x * 256 + threadIdx.x;
    if (i >= WROWS * NXF) return;
    int r = i / NXF, k = i - r * NXF;
    float v;
    if (r < 256)      v = (k < 512) ? W_ih[(long)r * DMSG_C + k] : W_hh[(long)r * DIM_C + (k - 512)];
    else if (r < 384) v = (k < 512) ? W_ih[(long)r * DMSG_C + k] : 0.0f;
    else              v = (k >= 512) ? W_hh[(long)(r - 128) * DIM_C + (k - 512)] : 0.0f;
    Wall[i] = f2bf(v);
}

template <int PASS>
__global__ __launch_bounds__(256) void gru_mfma_kernel(
    const float* __restrict__ memory, const float* __restrict__ last_update,
    const unsigned short* __restrict__ Wall,
    const float* __restrict__ b_ih, const float* __restrict__ b_hh,
    const float* __restrict__ edge_times, const float* __restrict__ edge_feat,
    const int* __restrict__ src, const int* __restrict__ dst,
    const int* __restrict__ idx,
    float* __restrict__ out_mem, float* __restrict__ out_lu)
{
    __shared__ __align__(16) unsigned short Xl[NODES_PB][LDSW];
    __shared__ int eidx[NODES_PB];
    const int t = threadIdx.x;
    const int base = blockIdx.x * NODES_PB;
    if (t < NODES_PB) eidx[t] = idx[base + t];
    __syncthreads();
    const int tt = t & 127;
    const int sh = t >> 7;
    const float wfreq = __expf(-0.16317532f * (float)tt);
    for (int s0 = 0; s0 < NODES_PB; s0 += 2) {
        const int s = s0 + sh;
        const int n = base + s;
        const int e = eidx[s];
        const int eu = (e >= 0) ? e : 0;
        const int other = (PASS == 0) ? dst[eu] : src[eu];
        const float mself = memory[(long)n * DIM_C + tt];
        const float moth  = memory[(long)other * DIM_C + tt];
        const float ef    = edge_feat[(long)eu * DIM_C + tt];
        const float dt    = edge_times[eu] - last_update[n];
        const float enc   = __cosf(dt * wfreq);
        const float hv    = (PASS == 0) ? mself : out_mem[(long)n * DIM_C + tt];
        Xl[s][tt]       = f2bf(mself);
        Xl[s][128 + tt] = f2bf(moth);
        Xl[s][256 + tt] = f2bf(ef);
        Xl[s][384 + tt] = f2bf(enc);
        Xl[s][512 + tt] = f2bf(hv);
    }
    __syncthreads();
    const int w = t >> 6, lane = t & 63;
    const int quad = lane >> 4, c = lane & 15;
    f32x4 acc[8][2];
#pragma unroll
    for (int i = 0; i < 8; ++i)
#pragma unroll
        for (int mt = 0; mt < 2; ++mt) acc[i][mt] = (f32x4){0.f, 0.f, 0.f, 0.f};
    const unsigned short* wrow[8];
#pragma unroll
    for (int i = 0; i < 8; ++i)
        wrow[i] = Wall + (long)((w + 4 * i) * 16 + c) * NXF + quad * 8;
    for (int kk = 0; kk < 16; ++kk) {
        const int k0 = kk * 32;
        bf16x8 a0 = *(const bf16x8*)&Xl[c][k0 + quad * 8];
        bf16x8 a1 = *(const bf16x8*)&Xl[16 + c][k0 + quad * 8];
#pragma unroll
        for (int i = 0; i < 6; ++i) {
            bf16x8 b = *(const bf16x8*)(wrow[i] + k0);
            acc[i][0] = __builtin_amdgcn_mfma_f32_16x16x32_bf16(a0, b, acc[i][0], 0, 0, 0);
            acc[i][1] = __builtin_amdgcn_mfma_f32_16x16x32_bf16(a1, b, acc[i][1], 0, 0, 0);
        }
    }
    for (int kk = 16; kk < 20; ++kk) {
        const int k0 = kk * 32;
        bf16x8 a0 = *(const bf16x8*)&Xl[c][k0 + quad * 8];
        bf16x8 a1 = *(const bf16x8*)&Xl[16 + c][k0 + quad * 8];
#pragma unroll
        for (int ii = 0; ii < 6; ++ii) {
            const int i = (ii < 4) ? ii : ii + 2;
            bf16x8 b = *(const bf16x8*)(wrow[i] + k0);
            acc[i][0] = __builtin_amdgcn_mfma_f32_16x16x32_bf16(a0, b, acc[i][0], 0, 0, 0);
            acc[i][1] = __builtin_amdgcn_mfma_f32_16x16x32_bf16(a1, b, acc[i][1], 0, 0, 0);
        }
    }
    const float* hsrc = (PASS == 0) ? memory : out_mem;
#pragma unroll
    for (int p = 0; p < 2; ++p) {
        const int j = (w + 4 * p) * 16 + c;
        const float br = b_ih[j] + b_hh[j];
        const float bz = b_ih[128 + j] + b_hh[128 + j];
        const float bi = b_ih[256 + j];
        const float bh = b_hh[256 + j];
#pragma unroll
        for (int mt = 0; mt < 2; ++mt) {
#pragma unroll
            for (int reg = 0; reg < 4; ++reg) {
                const int ml = mt * 16 + quad * 4 + reg;
                const int n = base + ml;
                const int e = eidx[ml];
                const float h = hsrc[(long)n * DIM_C + j];
                if (e >= 0) {
                    const float r  = sigmoidf_(acc[p][mt][reg] + br);
                    const float z  = sigmoidf_(acc[p + 2][mt][reg] + bz);
                    const float nn = tanhf_(acc[p + 4][mt][reg] + bi + r * (acc[p + 6][mt][reg] + bh));
                    out_mem[(long)n * DIM_C + j] = (1.0f - z) * nn + z * h;
                } else if (PASS == 0) {
                    out_mem[(long)n * DIM_C + j] = h;
                }
            }
        }
    }
    if (t < NODES_PB) {
        const int n = base + t;
        const int e = eidx[t];
        if (e >= 0)         out_lu[n] = edge_times[e];
        else if (PASS == 0) out_lu[n] = last_update[n];
    }
}

// =====================  LAUNCH  =====================
extern "C" void kernel_launch(void* const* d_in, const int* in_sizes, int n_in,
                              void* d_out, int out_size, void* d_ws, size_t ws_size,
                              hipStream_t stream) {
    const float* memory      = (const float*)d_in[0];
    const float* last_update = (const float*)d_in[1];
    const float* W_ih        = (const float*)d_in[2];
    const float* W_hh        = (const float*)d_in[3];
    const float* b_ih        = (const float*)d_in[4];
    const float* b_hh        = (const float*)d_in[5];
    const float* edge_times  = (const float*)d_in[6];
    const float* edge_feat   = (const float*)d_in[7];
    const int*   src         = (const int*)d_in[8];
    const int*   dst         = (const int*)d_in[9];

    float* out_mem = (float*)d_out;
    float* out_lu  = out_mem + (size_t)N_NODES_C * DIM_C;

    // ws layout (main path)
    const size_t sIdx  = (size_t)NODES_PAD * 4;           // 400384 B each
    const size_t sDt   = (size_t)NODES_PAD * 4;
    const size_t sWall = (size_t)32 * 20 * 1024;          // 655360 B
    const size_t sX    = (size_t)GROUPS_PAD * XKK * 1024; // ~76.9 MB each
    const size_t oIdxS = 0, oIdxD = oIdxS + sIdx, oDtS = oIdxD + sIdx, oDtD = oDtS + sDt;
    const size_t oWall = oDtD + sDt, oXs = oWall + sWall, oXd = oXs + sX;
    const size_t need  = oXd + sX;                        // ~149 MB

    if (ws_size >= need) {
        int* idx_s = (int*)((char*)d_ws + oIdxS);
        int* idx_d = (int*)((char*)d_ws + oIdxD);
        float* dt_s = (float*)((char*)d_ws + oDtS);
        float* dt_d = (float*)((char*)d_ws + oDtD);
        unsigned short* Wsw = (unsigned short*)((char*)d_ws + oWall);
        unsigned short* Xs  = (unsigned short*)((char*)d_ws + oXs);
        unsigned short* Xd  = (unsigned short*)((char*)d_ws + oXd);

        hipMemsetAsync(d_ws, 0xFF, 2 * sIdx, stream);     // idx arrays = -1
        scatter_last_kernel<<<(N_EDGES_C + 255) / 256, 256, 0, stream>>>(src, dst, idx_s, idx_d);
        build_wallsw_kernel<<<160, 256, 0, stream>>>(W_ih, W_hh, Wsw);
        gather_kernel<<<N_NODES_C / 16, 256, 0, stream>>>(
            memory, last_update, edge_times, edge_feat, src, dst,
            idx_s, idx_d, dt_s, dt_d, Xs, Xd, out_mem, out_lu);
        gemm_pass_kernel<0><<<GROUPS_PAD / 8, 512, 0, stream>>>(
            memory, Wsw, b_ih, b_hh, Xs, Xs, dt_s, idx_s, out_mem);
        gemm_pass_kernel<1><<<GROUPS_PAD / 8, 512, 0, stream>>>(
            memory, Wsw, b_ih, b_hh, Xd, Xs, dt_d, idx_d, out_mem);
    } else {
        // R2 fused fallback (needs ~1.5 MB ws)
        int* idx_s = (int*)d_ws;
        int* idx_d = idx_s + N_NODES_C;
        unsigned short* Wall = (unsigned short*)((char*)d_ws + 2 * N_NODES_C * sizeof(int));
        hipMemsetAsync(d_ws, 0xFF, 2 * N_NODES_C * sizeof(int), stream);
        scatter_last_kernel<<<(N_EDGES_C + 255) / 256, 256, 0, stream>>>(src, dst, idx_s, idx_d);
        build_wall_kernel<<<(WROWS * NXF + 255) / 256, 256, 0, stream>>>(W_ih, W_hh, Wall);
        gru_mfma_kernel<0><<<N_NODES_C / NODES_PB, 256, 0, stream>>>(
            memory, last_update, Wall, b_ih, b_hh, edge_times, edge_feat,
            src, dst, idx_s, out_mem, out_lu);
        gru_mfma_kernel<1><<<N_NODES_C / NODES_PB, 256, 0, stream>>>(
            memory, last_update, Wall, b_ih, b_hh, edge_times, edge_feat,
            src, dst, idx_d, out_mem, out_lu);
    }
}